// Round 6
// baseline (635.755 us; speedup 1.0000x reference)
//
#include <hip/hip_runtime.h>
#include <math.h>

#define T_ 2048
#define NH_ 8
#define HD_ 128

typedef unsigned short u16;
typedef short bf16x8 __attribute__((ext_vector_type(8)));
typedef float f32x4 __attribute__((ext_vector_type(4)));

__device__ __forceinline__ u16 f2bf(float f)
{
    unsigned u = __float_as_uint(f);
    return (u16)((u + 0x7FFFu + ((u >> 16) & 1u)) >> 16);
}
__device__ __forceinline__ float bf2f(u16 h)
{
    return __uint_as_float(((unsigned)h) << 16);
}
// fp32 -> (hi, lo) bf16 split; a ~= hi + lo, rel err ~2^-17
__device__ __forceinline__ void split1(float f, u16& h, u16& l)
{
    h = f2bf(f);
    l = f2bf(f - bf2f(h));
}

// elementwise split of x: [n] fp32 -> hi/lo bf16
__global__ __launch_bounds__(256) void cvt_split(const float* __restrict__ in,
                                                 u16* __restrict__ hi,
                                                 u16* __restrict__ lo, int n)
{
    int i = (blockIdx.x * 256 + threadIdx.x) * 4;
    if (i >= n) return;
    float4 v = *(const float4*)&in[i];
    u16 h0, l0, h1, l1, h2, l2, h3, l3;
    split1(v.x, h0, l0); split1(v.y, h1, l1);
    split1(v.z, h2, l2); split1(v.w, h3, l3);
    ushort4 hv = {h0, h1, h2, h3}, lv = {l0, l1, l2, l3};
    *(ushort4*)&hi[i] = hv;
    *(ushort4*)&lo[i] = lv;
}

// ---------------------------------------------------------------------------
// Weight convert + transpose: Bw element (k,c) at (c>>cs)*sn + k*sk + (c&cm)
// -> WT_hi/WT_lo [n][Kd] bf16 (k contiguous).  grid (Kd/32, Ncols/32), 256 thr.
// ---------------------------------------------------------------------------
__global__ __launch_bounds__(256) void cvt_wT(const float* __restrict__ Bw,
                                              u16* __restrict__ WTh,
                                              u16* __restrict__ WTl,
                                              int Kd, int cs, int cm, long sn, int sk)
{
    __shared__ u16 tH[32][33], tL[32][33];
    const int tid = threadIdx.x;
    const int tx = tid & 31, ty = tid >> 5;
    const int k0 = blockIdx.x * 32, c0 = blockIdx.y * 32;
    #pragma unroll
    for (int r = 0; r < 4; ++r) {
        int k = k0 + ty * 4 + r;
        int c = c0 + tx;
        float v = Bw[(long)(c >> cs) * sn + (long)k * sk + (c & cm)];
        u16 h, l; split1(v, h, l);
        tH[ty * 4 + r][tx] = h;
        tL[ty * 4 + r][tx] = l;
    }
    __syncthreads();
    #pragma unroll
    for (int r = 0; r < 4; ++r) {
        int n = c0 + ty * 4 + r;
        WTh[(long)n * Kd + k0 + tx] = tH[tx][ty * 4 + r];
        WTl[(long)n * Kd + k0 + tx] = tL[tx][ty * 4 + r];
    }
}

// ---------------------------------------------------------------------------
// Split-bf16 MFMA GEMM v3: register-prefetch software pipeline.
//   C[M,N] = act((Ah+Al) @ (Bh+Bl)), A hi/lo [M][Kd], B hi/lo [N][Kd].
// Tile 128x128, BK=32, 256 thr / 4 waves (64x64 quadrants).
// K-loop: ds_write staged regs -> barrier -> global_load NEXT step into regs
// (in flight during compute) -> ds_read frags + 48 MFMA -> barrier.
// Load latency is hidden behind the MFMA phase (fixes the round-3..5
// issue->drain->compute serialization of global_load_lds).
// 1D grid, XCD-aware swizzle: xcd=id&7 owns 4 m-strips (A window L2-resident),
// n-major so 4 same-n blocks share each B tile.
// ---------------------------------------------------------------------------
__global__ __launch_bounds__(256) void gemm_mfma(
    const u16* __restrict__ Ah, const u16* __restrict__ Al,
    const u16* __restrict__ Bh, const u16* __restrict__ Bl,
    float* __restrict__ C, int M, int N, int Kd, int relu)
{
    __shared__ __align__(16) u16 sAh[4][128][8], sAl[4][128][8];
    __shared__ __align__(16) u16 sBh[4][128][8], sBl[4][128][8];

    const int tid  = threadIdx.x;
    const int w    = tid >> 6;
    const int lane = tid & 63;

    // swizzle: m-tiles = 32 (M=4096); xcd = id&7 -> m in [xcd*4, xcd*4+4)
    const int id   = blockIdx.x;
    const int m0   = (((id & 7) << 2) + ((id >> 3) & 3)) * 128;
    const int n0   = (id >> 5) * 128;

    const int mw   = (w & 1) * 64, nw = (w >> 1) * 64;
    const int mr   = lane & 15, quad = lane >> 4;

    // wave w stages matrix w: 0->Ah, 1->Al, 2->Bh, 3->Bl
    const u16* P = (w == 0) ? Ah : (w == 1) ? Al : (w == 2) ? Bh : Bl;
    u16* D = (w == 0) ? &sAh[0][0][0] : (w == 1) ? &sAl[0][0][0]
           : (w == 2) ? &sBh[0][0][0] : &sBl[0][0][0];
    const long rbase = (w < 2) ? m0 : n0;
    const u16* Prow0 = P + (long)(rbase + lane) * Kd;        // half 0
    const u16* Prow1 = P + (long)(rbase + 64 + lane) * Kd;   // half 1

    f32x4 acc[4][4] = {};
    uint4 g[8];

    // prologue: prefetch K-step 0
    #pragma unroll
    for (int q = 0; q < 8; ++q) {
        int kq = q >> 1;
        const u16* gp = ((q & 1) ? Prow1 : Prow0) + kq * 8;
        g[q] = *(const uint4*)gp;
    }

    for (int k0 = 0; k0 < Kd; k0 += 32) {
        // commit staged regs to LDS (vmcnt waited here by register dependency)
        #pragma unroll
        for (int q = 0; q < 8; ++q) {
            int kq = q >> 1, half = q & 1;
            *(uint4*)(D + kq * 1024 + half * 512 + lane * 8) = g[q];
        }
        __syncthreads();

        // prefetch next K-step (overlaps with the MFMA phase below)
        if (k0 + 32 < Kd) {
            #pragma unroll
            for (int q = 0; q < 8; ++q) {
                int kq = q >> 1;
                const u16* gp = ((q & 1) ? Prow1 : Prow0) + k0 + 32 + kq * 8;
                g[q] = *(const uint4*)gp;
            }
        }

        bf16x8 fah[4], fal[4], fbh[4], fbl[4];
        #pragma unroll
        for (int i = 0; i < 4; ++i) {
            fah[i] = *(const bf16x8*)&sAh[quad][mw + i * 16 + mr][0];
            fal[i] = *(const bf16x8*)&sAl[quad][mw + i * 16 + mr][0];
            fbh[i] = *(const bf16x8*)&sBh[quad][nw + i * 16 + mr][0];
            fbl[i] = *(const bf16x8*)&sBl[quad][nw + i * 16 + mr][0];
        }
        #pragma unroll
        for (int i = 0; i < 4; ++i)
            #pragma unroll
            for (int j = 0; j < 4; ++j) {
                acc[i][j] = __builtin_amdgcn_mfma_f32_16x16x32_bf16(fah[i], fbh[j], acc[i][j], 0, 0, 0);
                acc[i][j] = __builtin_amdgcn_mfma_f32_16x16x32_bf16(fah[i], fbl[j], acc[i][j], 0, 0, 0);
                acc[i][j] = __builtin_amdgcn_mfma_f32_16x16x32_bf16(fal[i], fbh[j], acc[i][j], 0, 0, 0);
            }
        __syncthreads();
    }

    #pragma unroll
    for (int i = 0; i < 4; ++i)
        #pragma unroll
        for (int j = 0; j < 4; ++j)
            #pragma unroll
            for (int r = 0; r < 4; ++r) {
                int row = m0 + mw + i * 16 + quad * 4 + r;
                int col = n0 + nw + j * 16 + mr;
                float v = acc[i][j][r];
                if (relu) v = fmaxf(v, 0.f);
                C[(long)row * N + col] = v;
            }
}

// ---------------------------------------------------------------------------
// HEB = bf16(Q) @ MhT[h], batched over heads.  grid (M/128, NH), 256 thr.
// ---------------------------------------------------------------------------
__global__ __launch_bounds__(256) void heb_gemm(
    const u16* __restrict__ Qbf, const u16* __restrict__ MhT,
    u16* __restrict__ HEBbf)
{
    __shared__ __align__(16) u16 sA[4][128][8], sB[4][128][8];

    const int tid  = threadIdx.x;
    const int w    = tid >> 6;
    const int lane = tid & 63;
    const int m0   = blockIdx.x * 128;
    const int h    = blockIdx.y;
    const int mw   = w * 32;
    const int mr   = lane & 15, quad = lane >> 4;
    const u16* Bm  = MhT + h * 16384;

    f32x4 acc[2][8] = {};

    for (int k0 = 0; k0 < 128; k0 += 32) {
        #pragma unroll
        for (int u = 0; u < 4; ++u) {
            int c = (w & 1) * 4 + u;
            int kq = c >> 1, half = c & 1;
            const u16* src; u16* dst; long gofs;
            if (w < 2) {
                src = Qbf;
                dst = &sA[0][0][0] + kq * 1024 + half * 512;
                gofs = (long)(m0 + half * 64 + lane) * 1024 + h * 128 + k0 + kq * 8;
            } else {
                src = Bm;
                dst = &sB[0][0][0] + kq * 1024 + half * 512;
                gofs = (long)(half * 64 + lane) * 128 + k0 + kq * 8;
            }
            __builtin_amdgcn_global_load_lds(
                (const __attribute__((address_space(1))) unsigned int*)(src + gofs),
                (__attribute__((address_space(3))) unsigned int*)dst, 16, 0, 0);
        }
        __syncthreads();

        bf16x8 fa[2], fb[8];
        #pragma unroll
        for (int i = 0; i < 2; ++i)
            fa[i] = *(const bf16x8*)&sA[quad][mw + i * 16 + mr][0];
        #pragma unroll
        for (int j = 0; j < 8; ++j)
            fb[j] = *(const bf16x8*)&sB[quad][j * 16 + mr][0];
        #pragma unroll
        for (int i = 0; i < 2; ++i)
            #pragma unroll
            for (int j = 0; j < 8; ++j)
                acc[i][j] = __builtin_amdgcn_mfma_f32_16x16x32_bf16(fa[i], fb[j], acc[i][j], 0, 0, 0);
        __syncthreads();
    }

    #pragma unroll
    for (int i = 0; i < 2; ++i)
        #pragma unroll
        for (int j = 0; j < 8; ++j)
            #pragma unroll
            for (int r = 0; r < 4; ++r) {
                int row = m0 + mw + i * 16 + quad * 4 + r;
                int col = h * 128 + j * 16 + mr;
                HEBbf[(long)row * 1024 + col] = f2bf(acc[i][j][r]);
            }
}

// Qbf = bf16(QV cols 0..1023)
__global__ __launch_bounds__(256) void qcvt(const float* __restrict__ QV,
                                            u16* __restrict__ Qbf)
{
    int i4 = (blockIdx.x * 256 + threadIdx.x) * 4;
    int bt = i4 >> 10, j = i4 & 1023;
    float4 v = *(const float4*)&QV[(long)bt * 2048 + j];
    ushort4 o = {f2bf(v.x), f2bf(v.y), f2bf(v.z), f2bf(v.w)};
    *(ushort4*)&Qbf[i4] = o;
}

// ---------------------------------------------------------------------------
// sig chain (QV row stride 2048, Q = cols 0..1023)
// ---------------------------------------------------------------------------
__global__ void sig_part(const float* __restrict__ QV, float* __restrict__ P)
{
    int j  = blockIdx.x * 256 + threadIdx.x;
    int tc = blockIdx.y;
    int b  = blockIdx.z;
    float s = 0.f, s8 = 0.f;
    int t0 = tc * 256;
    for (int t = t0; t < t0 + 256; ++t) {
        float v = QV[((long)(b * T_ + t)) * 2048 + j];
        s += v;
        if ((t & 7) == 0) s8 += v;
    }
    long o = ((long)b * 8 + tc) * 1024 + j;
    P[o * 2]     = s;
    P[o * 2 + 1] = s8;
}

__global__ void sig_fin(const float* __restrict__ P, float* __restrict__ sig)
{
    int j = blockIdx.x * 256 + threadIdx.x;
    int b = blockIdx.y;
    float s = 0.f, s8 = 0.f;
    for (int tc = 0; tc < 8; ++tc) {
        long o = ((long)b * 8 + tc) * 1024 + j;
        s  += P[o * 2];
        s8 += P[o * 2 + 1];
    }
    sig[b * 1024 + j] = s * (1.0f / 2048.0f) + 0.5f * s8 * (1.0f / 256.0f);
}

__global__ void mlp1(const float* __restrict__ sig, const float* __restrict__ w1,
                     const float* __restrict__ b1, float* __restrict__ H)
{
    int o = blockIdx.x * 256 + threadIdx.x;
    int b = blockIdx.y;
    float a = 0.f;
    for (int k = 0; k < 1024; ++k)
        a += sig[b * 1024 + k] * w1[(long)k * 512 + o];
    a += b1[o];
    H[b * 512 + o] = 0.5f * a * (1.0f + erff(a * 0.70710678118f));
}

__global__ void mlp2(const float* __restrict__ H, const float* __restrict__ w2,
                     const float* __restrict__ b2, const float* __restrict__ base,
                     float* __restrict__ metric)
{
    int c = blockIdx.x * 256 + threadIdx.x;
    int b = blockIdx.y;
    float a = 0.f;
    for (int k = 0; k < 512; ++k)
        a += H[b * 512 + k] * w2[(long)k * 1024 + c];
    float mv = base[c] + 0.1f * (a + b2[c]);
    metric[b * 1024 + c] = fmaxf(mv, 0.f) + log1pf(expf(-fabsf(mv)));
}

// MhT[h][e][f] = sum_r U[h][f][r] * V[h][r][e], bf16 out
__global__ void hebbmat(const float* __restrict__ U, const float* __restrict__ Vh,
                        u16* __restrict__ MhT)
{
    int gid = blockIdx.x * 256 + threadIdx.x;
    int h = gid >> 14;
    int rem = gid & 16383;
    int e = rem >> 7;
    int f = rem & 127;
    float a = 0.f;
    #pragma unroll
    for (int r = 0; r < 32; ++r)
        a += U[(h * 128 + f) * 32 + r] * Vh[(h * 32 + r) * 128 + e];
    MhT[(h * 128 + e) * 128 + f] = f2bf(a);
}

// ---------------------------------------------------------------------------
// Context kernel (unchanged)
// ---------------------------------------------------------------------------
__global__ __launch_bounds__(256) void context_k(
    const float* __restrict__ QV, const float* __restrict__ metric,
    const u16* __restrict__ HEBbf,
    u16* __restrict__ CTh, u16* __restrict__ CTl)
{
    __shared__ float dq[4][64], wv[4][32];
    __shared__ int   wi[4][32];

    const int w    = threadIdx.x >> 6;
    const int lane = threadIdx.x & 63;
    const int gw   = blockIdx.x * 4 + w;
    const int h    = gw & 7;
    const int bt   = gw >> 3;
    const int t    = bt & (T_ - 1);
    const int b    = bt >> 11;

    const long qrow  = (long)bt * 2048 + h * 128;
    const long ctrow = (long)bt * 1024 + h * 128;

    const int e4     = (lane & 31) * 4;
    const int jhalf  = lane >> 5;
    const float4 qv  = *(const float4*)&QV[qrow + e4];
    const float4 mv  = *(const float4*)&metric[(long)(b * NH_ + h) * HD_ + e4];

    #pragma unroll 4
    for (int it = 0; it < 32; ++it) {
        int j = 2 * it + jhalf;
        int r = t - j; if (r < 0) r = 0;
        const float4 kv = *(const float4*)&QV[((long)(b * T_ + r)) * 2048 + h * 128 + e4];
        float dx = kv.x - qv.x;
        float dy = kv.y - qv.y;
        float dz = kv.z - qv.z;
        float de = kv.w - qv.w;
        float s = mv.x * dx * dx + mv.y * dy * dy + mv.z * dz * dz + mv.w * de * de;
        #pragma unroll
        for (int m = 16; m; m >>= 1) s += __shfl_xor(s, m, 64);
        if ((lane & 31) == 0) dq[w][j] = s;
    }

    float q0 = QV[qrow + lane], q1 = QV[qrow + 64 + lane];
    float ss = q0 * q0 + q1 * q1;
    #pragma unroll
    for (int s = 32; s; s >>= 1) ss += __shfl_xor(ss, s, 64);
    const float qn  = sqrtf(ss);
    const float inv = 1.0f / fmaxf(qn, 1e-12f);

    float d = sqrtf(dq[w][lane] + 1e-8f);
    int jj = lane;

    for (int k = 2; k <= 64; k <<= 1) {
        for (int s = k >> 1; s >= 1; s >>= 1) {
            float od = __shfl_xor(d, s, 64);
            int   oj = __shfl_xor(jj, s, 64);
            bool up    = ((lane & k) == 0);
            bool lower = ((lane & s) == 0);
            bool osm   = (od < d) || (od == d && oj < jj);
            if ((lower == up) ? osm : !osm) { d = od; jj = oj; }
        }
    }

    float wexp = (lane < 32) ? expf(-d) : 0.f;
    float tot = wexp;
    #pragma unroll
    for (int s = 32; s; s >>= 1) tot += __shfl_xor(tot, s, 64);
    float wn = wexp / (tot + 1e-8f);
    if (lane < 32) {
        wv[w][lane] = wn;
        int ii = t - jj; if (ii < 0) ii = 0;
        wi[w][lane] = ii;
    }

    float c0 = 0.f, c1 = 0.f;
    #pragma unroll 4
    for (int k = 0; k < 32; ++k) {
        float wk = wv[w][k];
        long vb = ((long)(b * T_ + wi[w][k])) * 2048 + 1024 + h * 128;
        c0 += wk * QV[vb + lane];
        c1 += wk * QV[vb + 64 + lane];
    }

    if (qn > 0.2f) {
        float s = 0.1f * inv;
        c0 += s * bf2f(HEBbf[ctrow + lane]);
        c1 += s * bf2f(HEBbf[ctrow + 64 + lane]);
    }

    u16 hh, ll;
    split1(q0 * c0, hh, ll);
    CTh[ctrow + lane] = hh; CTl[ctrow + lane] = ll;
    split1(q1 * c1, hh, ll);
    CTh[ctrow + 64 + lane] = hh; CTl[ctrow + 64 + lane] = ll;
}

// ---------------------------------------------------------------------------
extern "C" void kernel_launch(void* const* d_in, const int* in_sizes, int n_in,
                              void* d_out, int out_size, void* d_ws, size_t ws_size,
                              hipStream_t stream)
{
    const float* x     = (const float*)d_in[0];
    const float* enc_q = (const float*)d_in[1];
    const float* enc_v = (const float*)d_in[2];
    const float* w1    = (const float*)d_in[3];
    const float* b1    = (const float*)d_in[4];
    const float* w2    = (const float*)d_in[5];
    const float* b2    = (const float*)d_in[6];
    const float* base  = (const float*)d_in[7];
    const float* hU    = (const float*)d_in[8];
    const float* hV    = (const float*)d_in[9];
    const float* dec   = (const float*)d_in[10];
    float* out = (float*)d_out;
    float* ws  = (float*)d_ws;

    // ws (floats), peak 12.75M = 51 MB:
    float* QV  = ws;                        // [0, 8388608) fp32 [4096][2048]
    u16* wTh   = (u16*)(ws + 8388608);      // 2048*1024 u16 (dead after QV gemm)
    u16* wTl   = (u16*)(ws + 9437184);
    u16* CTh   = (u16*)(ws + 8388608);      // 4096*1024 u16 (after wT dead)
    u16* CTl   = (u16*)(ws + 10485760);
    u16* MhT   = (u16*)(ws + 12582912);     // 8*128*128 u16
    float* P   = ws + 12713984;
    float* sg  = ws + 12746752;
    float* Hh  = ws + 12748800;
    float* Me  = ws + 12749824;
    u16* wdTh  = (u16*)ws;                  // QV region, dead after context_k
    u16* wdTl  = (u16*)(ws + 524288);
    u16* xh    = (u16*)d_out;               // staging in d_out
    u16* xl    = xh + 4194304;
    u16* Qbf   = (u16*)d_out;               // after xh dead
    u16* HEBbf = (u16*)d_out + 4194304;     // after xl dead

    cvt_split<<<4096, 256, 0, stream>>>(x, xh, xl, 4194304);

    // merged weights: enc_q -> rows 0..1023, enc_v -> rows 1024..2047
    cvt_wT<<<dim3(32, 32), 256, 0, stream>>>(enc_q, wTh, wTl, 1024, 7, 127, 131072L, 128);
    cvt_wT<<<dim3(32, 32), 256, 0, stream>>>(enc_v, wTh + 1048576, wTl + 1048576,
                                             1024, 7, 127, 131072L, 128);
    // QV = relu(x @ [enc_q | enc_v]) — 512 blocks, 1D swizzled grid
    gemm_mfma<<<512, 256, 0, stream>>>(xh, xl, wTh, wTl, QV, 4096, 2048, 1024, 1);

    qcvt<<<4096, 256, 0, stream>>>(QV, Qbf);

    sig_part<<<dim3(4, 8, 2), 256, 0, stream>>>(QV, P);
    sig_fin <<<dim3(4, 2),    256, 0, stream>>>(P, sg);
    mlp1    <<<dim3(2, 2),    256, 0, stream>>>(sg, w1, b1, Hh);
    mlp2    <<<dim3(4, 2),    256, 0, stream>>>(Hh, w2, b2, base, Me);
    hebbmat <<<512,           256, 0, stream>>>(hU, hV, MhT);
    heb_gemm<<<dim3(32, 8),   256, 0, stream>>>(Qbf, MhT, HEBbf);

    context_k<<<8192, 256, 0, stream>>>(QV, Me, HEBbf, CTh, CTl);

    // out = CT @ decoder — 256 blocks, 1D swizzled grid
    cvt_wT<<<dim3(32, 32), 256, 0, stream>>>(dec, wdTh, wdTl, 1024, 30, 0x3fffffff, 0L, 1024);
    gemm_mfma<<<256, 256, 0, stream>>>(CTh, CTl, wdTh, wdTl, out, 4096, 1024, 1024, 0);
}

// Round 7
// 430.987 us; speedup vs baseline: 1.4751x; 1.4751x over previous
//
#include <hip/hip_runtime.h>
#include <math.h>

#define T_ 2048
#define NH_ 8
#define HD_ 128

typedef unsigned short u16;
typedef short bf16x8 __attribute__((ext_vector_type(8)));
typedef float f32x4 __attribute__((ext_vector_type(4)));

__device__ __forceinline__ u16 f2bf(float f)
{
    unsigned u = __float_as_uint(f);
    return (u16)((u + 0x7FFFu + ((u >> 16) & 1u)) >> 16);
}
__device__ __forceinline__ float bf2f(u16 h)
{
    return __uint_as_float(((unsigned)h) << 16);
}
// fp32 -> (hi, lo) bf16 split; a ~= hi + lo, rel err ~2^-17
__device__ __forceinline__ void split1(float f, u16& h, u16& l)
{
    h = f2bf(f);
    l = f2bf(f - bf2f(h));
}

// elementwise split of x: [n] fp32 -> hi/lo bf16
__global__ __launch_bounds__(256) void cvt_split(const float* __restrict__ in,
                                                 u16* __restrict__ hi,
                                                 u16* __restrict__ lo, int n)
{
    int i = (blockIdx.x * 256 + threadIdx.x) * 4;
    if (i >= n) return;
    float4 v = *(const float4*)&in[i];
    u16 h0, l0, h1, l1, h2, l2, h3, l3;
    split1(v.x, h0, l0); split1(v.y, h1, l1);
    split1(v.z, h2, l2); split1(v.w, h3, l3);
    ushort4 hv = {h0, h1, h2, h3}, lv = {l0, l1, l2, l3};
    *(ushort4*)&hi[i] = hv;
    *(ushort4*)&lo[i] = lv;
}

// ---------------------------------------------------------------------------
// Weight convert + transpose: Bw element (k,c) at (c>>cs)*sn + k*sk + (c&cm)
// -> WT_hi/WT_lo [n][Kd] bf16 (k contiguous).  grid (Kd/32, Ncols/32), 256 thr.
// ---------------------------------------------------------------------------
__global__ __launch_bounds__(256) void cvt_wT(const float* __restrict__ Bw,
                                              u16* __restrict__ WTh,
                                              u16* __restrict__ WTl,
                                              int Kd, int cs, int cm, long sn, int sk)
{
    __shared__ u16 tH[32][33], tL[32][33];
    const int tid = threadIdx.x;
    const int tx = tid & 31, ty = tid >> 5;
    const int k0 = blockIdx.x * 32, c0 = blockIdx.y * 32;
    #pragma unroll
    for (int r = 0; r < 4; ++r) {
        int k = k0 + ty * 4 + r;
        int c = c0 + tx;
        float v = Bw[(long)(c >> cs) * sn + (long)k * sk + (c & cm)];
        u16 h, l; split1(v, h, l);
        tH[ty * 4 + r][tx] = h;
        tL[ty * 4 + r][tx] = l;
    }
    __syncthreads();
    #pragma unroll
    for (int r = 0; r < 4; ++r) {
        int n = c0 + ty * 4 + r;
        WTh[(long)n * Kd + k0 + tx] = tH[tx][ty * 4 + r];
        WTl[(long)n * Kd + k0 + tx] = tL[tx][ty * 4 + r];
    }
}

// ---------------------------------------------------------------------------
// Split-bf16 MFMA GEMM v4: register-prefetch pipeline, spill-free.
// __launch_bounds__(256,1): round-6's (256) default made the allocator pick
// 68 VGPRs -> uint4 g[8] spilled to scratch -> 450 MB of HBM spill traffic.
// Named g0..g7 + wide budget keep the prefetch in VGPRs.
// Register prefetch rides ACROSS __syncthreads (no vmcnt(0) drain, unlike
// global_load_lds) — loads stay in flight during the whole MFMA phase.
// ---------------------------------------------------------------------------
__global__ __launch_bounds__(256, 1) void gemm_mfma(
    const u16* __restrict__ Ah, const u16* __restrict__ Al,
    const u16* __restrict__ Bh, const u16* __restrict__ Bl,
    float* __restrict__ C, int M, int N, int Kd, int relu)
{
    __shared__ __align__(16) u16 sAh[4][128][8], sAl[4][128][8];
    __shared__ __align__(16) u16 sBh[4][128][8], sBl[4][128][8];

    const int tid  = threadIdx.x;
    const int w    = tid >> 6;
    const int lane = tid & 63;

    // swizzle: m-tiles = 32 (M=4096); xcd = id&7 -> m in [xcd*4, xcd*4+4)
    const int id   = blockIdx.x;
    const int m0   = (((id & 7) << 2) + ((id >> 3) & 3)) * 128;
    const int n0   = (id >> 5) * 128;

    const int mw   = (w & 1) * 64, nw = (w >> 1) * 64;
    const int mr   = lane & 15, quad = lane >> 4;

    // wave w stages matrix w: 0->Ah, 1->Al, 2->Bh, 3->Bl
    const u16* P = (w == 0) ? Ah : (w == 1) ? Al : (w == 2) ? Bh : Bl;
    u16* D = (w == 0) ? &sAh[0][0][0] : (w == 1) ? &sAl[0][0][0]
           : (w == 2) ? &sBh[0][0][0] : &sBl[0][0][0];
    const long rbase = (w < 2) ? m0 : n0;
    const u16* Prow0 = P + (long)(rbase + lane) * Kd;        // half 0
    const u16* Prow1 = P + (long)(rbase + 64 + lane) * Kd;   // half 1

    f32x4 acc[4][4] = {};
    uint4 g0, g1, g2, g3, g4, g5, g6, g7;   // named: must stay in VGPRs

    // prologue: prefetch K-step 0   (gq: q=2*kq+half -> Prow{half} + kq*8)
    g0 = *(const uint4*)(Prow0 + 0);  g1 = *(const uint4*)(Prow1 + 0);
    g2 = *(const uint4*)(Prow0 + 8);  g3 = *(const uint4*)(Prow1 + 8);
    g4 = *(const uint4*)(Prow0 + 16); g5 = *(const uint4*)(Prow1 + 16);
    g6 = *(const uint4*)(Prow0 + 24); g7 = *(const uint4*)(Prow1 + 24);

    for (int k0 = 0; k0 < Kd; k0 += 32) {
        // commit staged regs to LDS
        *(uint4*)(D +    0 +   0 + lane * 8) = g0;
        *(uint4*)(D +    0 + 512 + lane * 8) = g1;
        *(uint4*)(D + 1024 +   0 + lane * 8) = g2;
        *(uint4*)(D + 1024 + 512 + lane * 8) = g3;
        *(uint4*)(D + 2048 +   0 + lane * 8) = g4;
        *(uint4*)(D + 2048 + 512 + lane * 8) = g5;
        *(uint4*)(D + 3072 +   0 + lane * 8) = g6;
        *(uint4*)(D + 3072 + 512 + lane * 8) = g7;
        __syncthreads();

        // prefetch next K-step (in flight during the MFMA phase below)
        if (k0 + 32 < Kd) {
            int kn = k0 + 32;
            g0 = *(const uint4*)(Prow0 + kn + 0);  g1 = *(const uint4*)(Prow1 + kn + 0);
            g2 = *(const uint4*)(Prow0 + kn + 8);  g3 = *(const uint4*)(Prow1 + kn + 8);
            g4 = *(const uint4*)(Prow0 + kn + 16); g5 = *(const uint4*)(Prow1 + kn + 16);
            g6 = *(const uint4*)(Prow0 + kn + 24); g7 = *(const uint4*)(Prow1 + kn + 24);
        }

        bf16x8 fah[4], fal[4], fbh[4], fbl[4];
        #pragma unroll
        for (int i = 0; i < 4; ++i) {
            fah[i] = *(const bf16x8*)&sAh[quad][mw + i * 16 + mr][0];
            fal[i] = *(const bf16x8*)&sAl[quad][mw + i * 16 + mr][0];
            fbh[i] = *(const bf16x8*)&sBh[quad][nw + i * 16 + mr][0];
            fbl[i] = *(const bf16x8*)&sBl[quad][nw + i * 16 + mr][0];
        }
        #pragma unroll
        for (int i = 0; i < 4; ++i)
            #pragma unroll
            for (int j = 0; j < 4; ++j) {
                acc[i][j] = __builtin_amdgcn_mfma_f32_16x16x32_bf16(fah[i], fbh[j], acc[i][j], 0, 0, 0);
                acc[i][j] = __builtin_amdgcn_mfma_f32_16x16x32_bf16(fah[i], fbl[j], acc[i][j], 0, 0, 0);
                acc[i][j] = __builtin_amdgcn_mfma_f32_16x16x32_bf16(fal[i], fbh[j], acc[i][j], 0, 0, 0);
            }
        __syncthreads();
    }

    #pragma unroll
    for (int i = 0; i < 4; ++i)
        #pragma unroll
        for (int j = 0; j < 4; ++j)
            #pragma unroll
            for (int r = 0; r < 4; ++r) {
                int row = m0 + mw + i * 16 + quad * 4 + r;
                int col = n0 + nw + j * 16 + mr;
                float v = acc[i][j][r];
                if (relu) v = fmaxf(v, 0.f);
                C[(long)row * N + col] = v;
            }
}

// ---------------------------------------------------------------------------
// HEB = bf16(Q) @ MhT[h], batched over heads.  grid (M/128, NH), 256 thr.
// ---------------------------------------------------------------------------
__global__ __launch_bounds__(256) void heb_gemm(
    const u16* __restrict__ Qbf, const u16* __restrict__ MhT,
    u16* __restrict__ HEBbf)
{
    __shared__ __align__(16) u16 sA[4][128][8], sB[4][128][8];

    const int tid  = threadIdx.x;
    const int w    = tid >> 6;
    const int lane = tid & 63;
    const int m0   = blockIdx.x * 128;
    const int h    = blockIdx.y;
    const int mw   = w * 32;
    const int mr   = lane & 15, quad = lane >> 4;
    const u16* Bm  = MhT + h * 16384;

    f32x4 acc[2][8] = {};

    for (int k0 = 0; k0 < 128; k0 += 32) {
        #pragma unroll
        for (int u = 0; u < 4; ++u) {
            int c = (w & 1) * 4 + u;
            int kq = c >> 1, half = c & 1;
            const u16* src; u16* dst; long gofs;
            if (w < 2) {
                src = Qbf;
                dst = &sA[0][0][0] + kq * 1024 + half * 512;
                gofs = (long)(m0 + half * 64 + lane) * 1024 + h * 128 + k0 + kq * 8;
            } else {
                src = Bm;
                dst = &sB[0][0][0] + kq * 1024 + half * 512;
                gofs = (long)(half * 64 + lane) * 128 + k0 + kq * 8;
            }
            __builtin_amdgcn_global_load_lds(
                (const __attribute__((address_space(1))) unsigned int*)(src + gofs),
                (__attribute__((address_space(3))) unsigned int*)dst, 16, 0, 0);
        }
        __syncthreads();

        bf16x8 fa[2], fb[8];
        #pragma unroll
        for (int i = 0; i < 2; ++i)
            fa[i] = *(const bf16x8*)&sA[quad][mw + i * 16 + mr][0];
        #pragma unroll
        for (int j = 0; j < 8; ++j)
            fb[j] = *(const bf16x8*)&sB[quad][j * 16 + mr][0];
        #pragma unroll
        for (int i = 0; i < 2; ++i)
            #pragma unroll
            for (int j = 0; j < 8; ++j)
                acc[i][j] = __builtin_amdgcn_mfma_f32_16x16x32_bf16(fa[i], fb[j], acc[i][j], 0, 0, 0);
        __syncthreads();
    }

    #pragma unroll
    for (int i = 0; i < 2; ++i)
        #pragma unroll
        for (int j = 0; j < 8; ++j)
            #pragma unroll
            for (int r = 0; r < 4; ++r) {
                int row = m0 + mw + i * 16 + quad * 4 + r;
                int col = h * 128 + j * 16 + mr;
                HEBbf[(long)row * 1024 + col] = f2bf(acc[i][j][r]);
            }
}

// Qbf = bf16(QV cols 0..1023)
__global__ __launch_bounds__(256) void qcvt(const float* __restrict__ QV,
                                            u16* __restrict__ Qbf)
{
    int i4 = (blockIdx.x * 256 + threadIdx.x) * 4;
    int bt = i4 >> 10, j = i4 & 1023;
    float4 v = *(const float4*)&QV[(long)bt * 2048 + j];
    ushort4 o = {f2bf(v.x), f2bf(v.y), f2bf(v.z), f2bf(v.w)};
    *(ushort4*)&Qbf[i4] = o;
}

// ---------------------------------------------------------------------------
// sig chain (QV row stride 2048, Q = cols 0..1023)
// ---------------------------------------------------------------------------
__global__ void sig_part(const float* __restrict__ QV, float* __restrict__ P)
{
    int j  = blockIdx.x * 256 + threadIdx.x;
    int tc = blockIdx.y;
    int b  = blockIdx.z;
    float s = 0.f, s8 = 0.f;
    int t0 = tc * 256;
    for (int t = t0; t < t0 + 256; ++t) {
        float v = QV[((long)(b * T_ + t)) * 2048 + j];
        s += v;
        if ((t & 7) == 0) s8 += v;
    }
    long o = ((long)b * 8 + tc) * 1024 + j;
    P[o * 2]     = s;
    P[o * 2 + 1] = s8;
}

__global__ void sig_fin(const float* __restrict__ P, float* __restrict__ sig)
{
    int j = blockIdx.x * 256 + threadIdx.x;
    int b = blockIdx.y;
    float s = 0.f, s8 = 0.f;
    for (int tc = 0; tc < 8; ++tc) {
        long o = ((long)b * 8 + tc) * 1024 + j;
        s  += P[o * 2];
        s8 += P[o * 2 + 1];
    }
    sig[b * 1024 + j] = s * (1.0f / 2048.0f) + 0.5f * s8 * (1.0f / 256.0f);
}

__global__ void mlp1(const float* __restrict__ sig, const float* __restrict__ w1,
                     const float* __restrict__ b1, float* __restrict__ H)
{
    int o = blockIdx.x * 256 + threadIdx.x;
    int b = blockIdx.y;
    float a = 0.f;
    for (int k = 0; k < 1024; ++k)
        a += sig[b * 1024 + k] * w1[(long)k * 512 + o];
    a += b1[o];
    H[b * 512 + o] = 0.5f * a * (1.0f + erff(a * 0.70710678118f));
}

__global__ void mlp2(const float* __restrict__ H, const float* __restrict__ w2,
                     const float* __restrict__ b2, const float* __restrict__ base,
                     float* __restrict__ metric)
{
    int c = blockIdx.x * 256 + threadIdx.x;
    int b = blockIdx.y;
    float a = 0.f;
    for (int k = 0; k < 512; ++k)
        a += H[b * 512 + k] * w2[(long)k * 1024 + c];
    float mv = base[c] + 0.1f * (a + b2[c]);
    metric[b * 1024 + c] = fmaxf(mv, 0.f) + log1pf(expf(-fabsf(mv)));
}

// MhT[h][e][f] = sum_r U[h][f][r] * V[h][r][e], bf16 out
__global__ void hebbmat(const float* __restrict__ U, const float* __restrict__ Vh,
                        u16* __restrict__ MhT)
{
    int gid = blockIdx.x * 256 + threadIdx.x;
    int h = gid >> 14;
    int rem = gid & 16383;
    int e = rem >> 7;
    int f = rem & 127;
    float a = 0.f;
    #pragma unroll
    for (int r = 0; r < 32; ++r)
        a += U[(h * 128 + f) * 32 + r] * Vh[(h * 32 + r) * 128 + e];
    MhT[(h * 128 + e) * 128 + f] = f2bf(a);
}

// ---------------------------------------------------------------------------
// Context kernel (unchanged)
// ---------------------------------------------------------------------------
__global__ __launch_bounds__(256) void context_k(
    const float* __restrict__ QV, const float* __restrict__ metric,
    const u16* __restrict__ HEBbf,
    u16* __restrict__ CTh, u16* __restrict__ CTl)
{
    __shared__ float dq[4][64], wv[4][32];
    __shared__ int   wi[4][32];

    const int w    = threadIdx.x >> 6;
    const int lane = threadIdx.x & 63;
    const int gw   = blockIdx.x * 4 + w;
    const int h    = gw & 7;
    const int bt   = gw >> 3;
    const int t    = bt & (T_ - 1);
    const int b    = bt >> 11;

    const long qrow  = (long)bt * 2048 + h * 128;
    const long ctrow = (long)bt * 1024 + h * 128;

    const int e4     = (lane & 31) * 4;
    const int jhalf  = lane >> 5;
    const float4 qv  = *(const float4*)&QV[qrow + e4];
    const float4 mv  = *(const float4*)&metric[(long)(b * NH_ + h) * HD_ + e4];

    #pragma unroll 4
    for (int it = 0; it < 32; ++it) {
        int j = 2 * it + jhalf;
        int r = t - j; if (r < 0) r = 0;
        const float4 kv = *(const float4*)&QV[((long)(b * T_ + r)) * 2048 + h * 128 + e4];
        float dx = kv.x - qv.x;
        float dy = kv.y - qv.y;
        float dz = kv.z - qv.z;
        float de = kv.w - qv.w;
        float s = mv.x * dx * dx + mv.y * dy * dy + mv.z * dz * dz + mv.w * de * de;
        #pragma unroll
        for (int m = 16; m; m >>= 1) s += __shfl_xor(s, m, 64);
        if ((lane & 31) == 0) dq[w][j] = s;
    }

    float q0 = QV[qrow + lane], q1 = QV[qrow + 64 + lane];
    float ss = q0 * q0 + q1 * q1;
    #pragma unroll
    for (int s = 32; s; s >>= 1) ss += __shfl_xor(ss, s, 64);
    const float qn  = sqrtf(ss);
    const float inv = 1.0f / fmaxf(qn, 1e-12f);

    float d = sqrtf(dq[w][lane] + 1e-8f);
    int jj = lane;

    for (int k = 2; k <= 64; k <<= 1) {
        for (int s = k >> 1; s >= 1; s >>= 1) {
            float od = __shfl_xor(d, s, 64);
            int   oj = __shfl_xor(jj, s, 64);
            bool up    = ((lane & k) == 0);
            bool lower = ((lane & s) == 0);
            bool osm   = (od < d) || (od == d && oj < jj);
            if ((lower == up) ? osm : !osm) { d = od; jj = oj; }
        }
    }

    float wexp = (lane < 32) ? expf(-d) : 0.f;
    float tot = wexp;
    #pragma unroll
    for (int s = 32; s; s >>= 1) tot += __shfl_xor(tot, s, 64);
    float wn = wexp / (tot + 1e-8f);
    if (lane < 32) {
        wv[w][lane] = wn;
        int ii = t - jj; if (ii < 0) ii = 0;
        wi[w][lane] = ii;
    }

    float c0 = 0.f, c1 = 0.f;
    #pragma unroll 4
    for (int k = 0; k < 32; ++k) {
        float wk = wv[w][k];
        long vb = ((long)(b * T_ + wi[w][k])) * 2048 + 1024 + h * 128;
        c0 += wk * QV[vb + lane];
        c1 += wk * QV[vb + 64 + lane];
    }

    if (qn > 0.2f) {
        float s = 0.1f * inv;
        c0 += s * bf2f(HEBbf[ctrow + lane]);
        c1 += s * bf2f(HEBbf[ctrow + 64 + lane]);
    }

    u16 hh, ll;
    split1(q0 * c0, hh, ll);
    CTh[ctrow + lane] = hh; CTl[ctrow + lane] = ll;
    split1(q1 * c1, hh, ll);
    CTh[ctrow + 64 + lane] = hh; CTl[ctrow + 64 + lane] = ll;
}

// ---------------------------------------------------------------------------
extern "C" void kernel_launch(void* const* d_in, const int* in_sizes, int n_in,
                              void* d_out, int out_size, void* d_ws, size_t ws_size,
                              hipStream_t stream)
{
    const float* x     = (const float*)d_in[0];
    const float* enc_q = (const float*)d_in[1];
    const float* enc_v = (const float*)d_in[2];
    const float* w1    = (const float*)d_in[3];
    const float* b1    = (const float*)d_in[4];
    const float* w2    = (const float*)d_in[5];
    const float* b2    = (const float*)d_in[6];
    const float* base  = (const float*)d_in[7];
    const float* hU    = (const float*)d_in[8];
    const float* hV    = (const float*)d_in[9];
    const float* dec   = (const float*)d_in[10];
    float* out = (float*)d_out;
    float* ws  = (float*)d_ws;

    // ws (floats), peak 12.75M = 51 MB:
    float* QV  = ws;                        // [0, 8388608) fp32 [4096][2048]
    u16* wTh   = (u16*)(ws + 8388608);      // 2048*1024 u16 (dead after QV gemm)
    u16* wTl   = (u16*)(ws + 9437184);
    u16* CTh   = (u16*)(ws + 8388608);      // 4096*1024 u16 (after wT dead)
    u16* CTl   = (u16*)(ws + 10485760);
    u16* MhT   = (u16*)(ws + 12582912);     // 8*128*128 u16
    float* P   = ws + 12713984;
    float* sg  = ws + 12746752;
    float* Hh  = ws + 12748800;
    float* Me  = ws + 12749824;
    u16* wdTh  = (u16*)ws;                  // QV region, dead after context_k
    u16* wdTl  = (u16*)(ws + 524288);
    u16* xh    = (u16*)d_out;               // staging in d_out
    u16* xl    = xh + 4194304;
    u16* Qbf   = (u16*)d_out;               // after xh dead
    u16* HEBbf = (u16*)d_out + 4194304;     // after xl dead

    cvt_split<<<4096, 256, 0, stream>>>(x, xh, xl, 4194304);

    // merged weights: enc_q -> rows 0..1023, enc_v -> rows 1024..2047
    cvt_wT<<<dim3(32, 32), 256, 0, stream>>>(enc_q, wTh, wTl, 1024, 7, 127, 131072L, 128);
    cvt_wT<<<dim3(32, 32), 256, 0, stream>>>(enc_v, wTh + 1048576, wTl + 1048576,
                                             1024, 7, 127, 131072L, 128);
    // QV = relu(x @ [enc_q | enc_v]) — 512 blocks, 1D swizzled grid
    gemm_mfma<<<512, 256, 0, stream>>>(xh, xl, wTh, wTl, QV, 4096, 2048, 1024, 1);

    qcvt<<<4096, 256, 0, stream>>>(QV, Qbf);

    sig_part<<<dim3(4, 8, 2), 256, 0, stream>>>(QV, P);
    sig_fin <<<dim3(4, 2),    256, 0, stream>>>(P, sg);
    mlp1    <<<dim3(2, 2),    256, 0, stream>>>(sg, w1, b1, Hh);
    mlp2    <<<dim3(4, 2),    256, 0, stream>>>(Hh, w2, b2, base, Me);
    hebbmat <<<512,           256, 0, stream>>>(hU, hV, MhT);
    heb_gemm<<<dim3(32, 8),   256, 0, stream>>>(Qbf, MhT, HEBbf);

    context_k<<<8192, 256, 0, stream>>>(QV, Me, HEBbf, CTh, CTl);

    // out = CT @ decoder — 256 blocks, 1D swizzled grid
    cvt_wT<<<dim3(32, 32), 256, 0, stream>>>(dec, wdTh, wdTl, 1024, 30, 0x3fffffff, 0L, 1024);
    gemm_mfma<<<256, 256, 0, stream>>>(CTh, CTl, wdTh, wdTl, out, 4096, 1024, 1024, 0);
}

// Round 8
// 386.213 us; speedup vs baseline: 1.6461x; 1.1159x over previous
//
#include <hip/hip_runtime.h>
#include <math.h>

#define T_ 2048
#define NH_ 8
#define HD_ 128

typedef unsigned short u16;
typedef short bf16x8 __attribute__((ext_vector_type(8)));
typedef float f32x4 __attribute__((ext_vector_type(4)));

__device__ __forceinline__ u16 f2bf(float f)
{
    unsigned u = __float_as_uint(f);
    return (u16)((u + 0x7FFFu + ((u >> 16) & 1u)) >> 16);
}
__device__ __forceinline__ float bf2f(u16 h)
{
    return __uint_as_float(((unsigned)h) << 16);
}
// fp32 -> (hi, lo) bf16 split; a ~= hi + lo, rel err ~2^-17
__device__ __forceinline__ void split1(float f, u16& h, u16& l)
{
    h = f2bf(f);
    l = f2bf(f - bf2f(h));
}

// elementwise split of x: [n] fp32 -> hi/lo bf16
__global__ __launch_bounds__(256) void cvt_split(const float* __restrict__ in,
                                                 u16* __restrict__ hi,
                                                 u16* __restrict__ lo, int n)
{
    int i = (blockIdx.x * 256 + threadIdx.x) * 4;
    if (i >= n) return;
    float4 v = *(const float4*)&in[i];
    u16 h0, l0, h1, l1, h2, l2, h3, l3;
    split1(v.x, h0, l0); split1(v.y, h1, l1);
    split1(v.z, h2, l2); split1(v.w, h3, l3);
    ushort4 hv = {h0, h1, h2, h3}, lv = {l0, l1, l2, l3};
    *(ushort4*)&hi[i] = hv;
    *(ushort4*)&lo[i] = lv;
}

// ---------------------------------------------------------------------------
// Weight convert + transpose -> [n][Kd] bf16 hi/lo (k contiguous).
// ---------------------------------------------------------------------------
__global__ __launch_bounds__(256) void cvt_wT(const float* __restrict__ Bw,
                                              u16* __restrict__ WTh,
                                              u16* __restrict__ WTl,
                                              int Kd, int cs, int cm, long sn, int sk)
{
    __shared__ u16 tH[32][33], tL[32][33];
    const int tid = threadIdx.x;
    const int tx = tid & 31, ty = tid >> 5;
    const int k0 = blockIdx.x * 32, c0 = blockIdx.y * 32;
    #pragma unroll
    for (int r = 0; r < 4; ++r) {
        int k = k0 + ty * 4 + r;
        int c = c0 + tx;
        float v = Bw[(long)(c >> cs) * sn + (long)k * sk + (c & cm)];
        u16 h, l; split1(v, h, l);
        tH[ty * 4 + r][tx] = h;
        tL[ty * 4 + r][tx] = l;
    }
    __syncthreads();
    #pragma unroll
    for (int r = 0; r < 4; ++r) {
        int n = c0 + ty * 4 + r;
        WTh[(long)n * Kd + k0 + tx] = tH[tx][ty * 4 + r];
        WTl[(long)n * Kd + k0 + tx] = tL[tx][ty * 4 + r];
    }
}

// ---------------------------------------------------------------------------
// Split-bf16 MFMA GEMM v4 (round-7, proven): register-prefetch pipeline.
// ---------------------------------------------------------------------------
__global__ __launch_bounds__(256, 1) void gemm_mfma(
    const u16* __restrict__ Ah, const u16* __restrict__ Al,
    const u16* __restrict__ Bh, const u16* __restrict__ Bl,
    float* __restrict__ C, int M, int N, int Kd, int relu)
{
    __shared__ __align__(16) u16 sAh[4][128][8], sAl[4][128][8];
    __shared__ __align__(16) u16 sBh[4][128][8], sBl[4][128][8];

    const int tid  = threadIdx.x;
    const int w    = tid >> 6;
    const int lane = tid & 63;

    const int id   = blockIdx.x;
    const int m0   = (((id & 7) << 2) + ((id >> 3) & 3)) * 128;
    const int n0   = (id >> 5) * 128;

    const int mw   = (w & 1) * 64, nw = (w >> 1) * 64;
    const int mr   = lane & 15, quad = lane >> 4;

    const u16* P = (w == 0) ? Ah : (w == 1) ? Al : (w == 2) ? Bh : Bl;
    u16* D = (w == 0) ? &sAh[0][0][0] : (w == 1) ? &sAl[0][0][0]
           : (w == 2) ? &sBh[0][0][0] : &sBl[0][0][0];
    const long rbase = (w < 2) ? m0 : n0;
    const u16* Prow0 = P + (long)(rbase + lane) * Kd;
    const u16* Prow1 = P + (long)(rbase + 64 + lane) * Kd;

    f32x4 acc[4][4] = {};
    uint4 g0, g1, g2, g3, g4, g5, g6, g7;

    g0 = *(const uint4*)(Prow0 + 0);  g1 = *(const uint4*)(Prow1 + 0);
    g2 = *(const uint4*)(Prow0 + 8);  g3 = *(const uint4*)(Prow1 + 8);
    g4 = *(const uint4*)(Prow0 + 16); g5 = *(const uint4*)(Prow1 + 16);
    g6 = *(const uint4*)(Prow0 + 24); g7 = *(const uint4*)(Prow1 + 24);

    for (int k0 = 0; k0 < Kd; k0 += 32) {
        *(uint4*)(D +    0 +   0 + lane * 8) = g0;
        *(uint4*)(D +    0 + 512 + lane * 8) = g1;
        *(uint4*)(D + 1024 +   0 + lane * 8) = g2;
        *(uint4*)(D + 1024 + 512 + lane * 8) = g3;
        *(uint4*)(D + 2048 +   0 + lane * 8) = g4;
        *(uint4*)(D + 2048 + 512 + lane * 8) = g5;
        *(uint4*)(D + 3072 +   0 + lane * 8) = g6;
        *(uint4*)(D + 3072 + 512 + lane * 8) = g7;
        __syncthreads();

        if (k0 + 32 < Kd) {
            int kn = k0 + 32;
            g0 = *(const uint4*)(Prow0 + kn + 0);  g1 = *(const uint4*)(Prow1 + kn + 0);
            g2 = *(const uint4*)(Prow0 + kn + 8);  g3 = *(const uint4*)(Prow1 + kn + 8);
            g4 = *(const uint4*)(Prow0 + kn + 16); g5 = *(const uint4*)(Prow1 + kn + 16);
            g6 = *(const uint4*)(Prow0 + kn + 24); g7 = *(const uint4*)(Prow1 + kn + 24);
        }

        bf16x8 fah[4], fal[4], fbh[4], fbl[4];
        #pragma unroll
        for (int i = 0; i < 4; ++i) {
            fah[i] = *(const bf16x8*)&sAh[quad][mw + i * 16 + mr][0];
            fal[i] = *(const bf16x8*)&sAl[quad][mw + i * 16 + mr][0];
            fbh[i] = *(const bf16x8*)&sBh[quad][nw + i * 16 + mr][0];
            fbl[i] = *(const bf16x8*)&sBl[quad][nw + i * 16 + mr][0];
        }
        #pragma unroll
        for (int i = 0; i < 4; ++i)
            #pragma unroll
            for (int j = 0; j < 4; ++j) {
                acc[i][j] = __builtin_amdgcn_mfma_f32_16x16x32_bf16(fah[i], fbh[j], acc[i][j], 0, 0, 0);
                acc[i][j] = __builtin_amdgcn_mfma_f32_16x16x32_bf16(fah[i], fbl[j], acc[i][j], 0, 0, 0);
                acc[i][j] = __builtin_amdgcn_mfma_f32_16x16x32_bf16(fal[i], fbh[j], acc[i][j], 0, 0, 0);
            }
        __syncthreads();
    }

    #pragma unroll
    for (int i = 0; i < 4; ++i)
        #pragma unroll
        for (int j = 0; j < 4; ++j)
            #pragma unroll
            for (int r = 0; r < 4; ++r) {
                int row = m0 + mw + i * 16 + quad * 4 + r;
                int col = n0 + nw + j * 16 + mr;
                float v = acc[i][j][r];
                if (relu) v = fmaxf(v, 0.f);
                C[(long)row * N + col] = v;
            }
}

// ---------------------------------------------------------------------------
// HEB = bf16(Q) @ MhT[h], batched over heads.
// ---------------------------------------------------------------------------
__global__ __launch_bounds__(256) void heb_gemm(
    const u16* __restrict__ Qbf, const u16* __restrict__ MhT,
    u16* __restrict__ HEBbf)
{
    __shared__ __align__(16) u16 sA[4][128][8], sB[4][128][8];

    const int tid  = threadIdx.x;
    const int w    = tid >> 6;
    const int lane = tid & 63;
    const int m0   = blockIdx.x * 128;
    const int h    = blockIdx.y;
    const int mw   = w * 32;
    const int mr   = lane & 15, quad = lane >> 4;
    const u16* Bm  = MhT + h * 16384;

    f32x4 acc[2][8] = {};

    for (int k0 = 0; k0 < 128; k0 += 32) {
        #pragma unroll
        for (int u = 0; u < 4; ++u) {
            int c = (w & 1) * 4 + u;
            int kq = c >> 1, half = c & 1;
            const u16* src; u16* dst; long gofs;
            if (w < 2) {
                src = Qbf;
                dst = &sA[0][0][0] + kq * 1024 + half * 512;
                gofs = (long)(m0 + half * 64 + lane) * 1024 + h * 128 + k0 + kq * 8;
            } else {
                src = Bm;
                dst = &sB[0][0][0] + kq * 1024 + half * 512;
                gofs = (long)(half * 64 + lane) * 128 + k0 + kq * 8;
            }
            __builtin_amdgcn_global_load_lds(
                (const __attribute__((address_space(1))) unsigned int*)(src + gofs),
                (__attribute__((address_space(3))) unsigned int*)dst, 16, 0, 0);
        }
        __syncthreads();

        bf16x8 fa[2], fb[8];
        #pragma unroll
        for (int i = 0; i < 2; ++i)
            fa[i] = *(const bf16x8*)&sA[quad][mw + i * 16 + mr][0];
        #pragma unroll
        for (int j = 0; j < 8; ++j)
            fb[j] = *(const bf16x8*)&sB[quad][j * 16 + mr][0];
        #pragma unroll
        for (int i = 0; i < 2; ++i)
            #pragma unroll
            for (int j = 0; j < 8; ++j)
                acc[i][j] = __builtin_amdgcn_mfma_f32_16x16x32_bf16(fa[i], fb[j], acc[i][j], 0, 0, 0);
        __syncthreads();
    }

    #pragma unroll
    for (int i = 0; i < 2; ++i)
        #pragma unroll
        for (int j = 0; j < 8; ++j)
            #pragma unroll
            for (int r = 0; r < 4; ++r) {
                int row = m0 + mw + i * 16 + quad * 4 + r;
                int col = h * 128 + j * 16 + mr;
                HEBbf[(long)row * 1024 + col] = f2bf(acc[i][j][r]);
            }
}

// Qbf = bf16(QV cols 0..1023)
__global__ __launch_bounds__(256) void qcvt(const float* __restrict__ QV,
                                            u16* __restrict__ Qbf)
{
    int i4 = (blockIdx.x * 256 + threadIdx.x) * 4;
    int bt = i4 >> 10, j = i4 & 1023;
    float4 v = *(const float4*)&QV[(long)bt * 2048 + j];
    ushort4 o = {f2bf(v.x), f2bf(v.y), f2bf(v.z), f2bf(v.w)};
    *(ushort4*)&Qbf[i4] = o;
}

// ---------------------------------------------------------------------------
// ustage: U[b][h][t][e] = sqrt(metric)*q, split hi/lo bf16; n = |u|^2 fp32.
// 4M elements; one 32-lane subgroup per (bh,t) row.
// ---------------------------------------------------------------------------
__global__ __launch_bounds__(256) void ustage(const float* __restrict__ QV,
                                              const float* __restrict__ Me,
                                              u16* __restrict__ Uh, u16* __restrict__ Ul,
                                              float* __restrict__ nArr)
{
    int gid4 = (blockIdx.x * 256 + threadIdx.x) * 4;   // over 2*8*2048*128
    int e4 = gid4 & 127;
    int t  = (gid4 >> 7) & 2047;
    int bh = gid4 >> 18;
    int b  = bh >> 3, h = bh & 7;
    float4 q = *(const float4*)&QV[((long)(b * 2048 + t)) * 2048 + h * 128 + e4];
    float4 m = *(const float4*)&Me[bh * 128 + e4];
    float ux = sqrtf(m.x) * q.x, uy = sqrtf(m.y) * q.y;
    float uz = sqrtf(m.z) * q.z, uw = sqrtf(m.w) * q.w;
    u16 h0, l0, h1, l1, h2, l2, h3, l3;
    split1(ux, h0, l0); split1(uy, h1, l1);
    split1(uz, h2, l2); split1(uw, h3, l3);
    ushort4 hv = {h0, h1, h2, h3}, lv = {l0, l1, l2, l3};
    *(ushort4*)&Uh[gid4] = hv;
    *(ushort4*)&Ul[gid4] = lv;
    float ps = ux * ux + uy * uy + uz * uz + uw * uw;
    #pragma unroll
    for (int mm = 16; mm; mm >>= 1) ps += __shfl_xor(ps, mm, 64);
    if ((threadIdx.x & 31) == 0) nArr[gid4 >> 7] = ps;
}

// ---------------------------------------------------------------------------
// dist_gemm: banded d^2 via split-bf16 MFMA.
// Block = (bh, 64-t tile). A = U rows [t0,t0+64), B = U rows [t0-64,t0+64).
// band[bh][t][j] = n[t] + n[t-j] - 2*S(t,t-j), j=0..63 (j>t entries unused).
// ---------------------------------------------------------------------------
__global__ __launch_bounds__(256, 1) void dist_gemm(
    const u16* __restrict__ Uh, const u16* __restrict__ Ul,
    const float* __restrict__ nArr, float* __restrict__ band)
{
    __shared__ __align__(16) u16 sAh[4][64][8],  sAl[4][64][8];
    __shared__ __align__(16) u16 sBh[4][128][8], sBl[4][128][8];
    __shared__ float epi[4][16][128];

    const int tid  = threadIdx.x;
    const int w    = tid >> 6;
    const int lane = tid & 63;
    const int mr   = lane & 15, quad = lane >> 4;
    const int bid  = blockIdx.x;
    const int tile = bid & 31, bh = bid >> 5;
    const int t0   = tile * 64;
    const long ub  = (long)bh * 2048 * 128;   // u16 offset

    // chunk descriptors: c = i*256+tid; [0,256)=A-hi [256,512)=A-lo
    // [512,1024)=B-hi [1024,1536)=B-lo.  A: row=c&63, kq=(c>>6)&3.
    // B: cb=c-512, row=cb&127, kq=(cb>>7)&3.
    const u16 *s0, *s1, *s2, *s3, *s4, *s5;
    u16 *d0, *d1, *d2, *d3, *d4, *d5;
    long o0, o1, o2, o3, o4, o5;
    {
        auto mk = [&](int i, const u16*& src, u16*& dst, long& ofs) {
            int c = i * 256 + tid;
            if (c < 512) {
                int row = c & 63, kq = (c >> 6) & 3;
                src = (c < 256) ? Uh : Ul;
                ofs = ub + (long)(t0 + row) * 128 + kq * 8;
                dst = ((c < 256) ? &sAh[0][0][0] : &sAl[0][0][0]) + kq * 512 + row * 8;
            } else {
                int cb = c - 512;
                int row = cb & 127, kq = (cb >> 7) & 3;
                src = (cb < 512) ? Uh : Ul;
                ofs = ub + (long)(t0 - 64 + row) * 128 + kq * 8;
                dst = ((cb < 512) ? &sBh[0][0][0] : &sBl[0][0][0]) + kq * 1024 + row * 8;
            }
        };
        mk(0, s0, d0, o0); mk(1, s1, d1, o1); mk(2, s2, d2, o2);
        mk(3, s3, d3, o3); mk(4, s4, d4, o4); mk(5, s5, d5, o5);
    }

    f32x4 acc[8] = {};
    uint4 g0, g1, g2, g3, g4, g5;
    g0 = *(const uint4*)(s0 + o0); g1 = *(const uint4*)(s1 + o1);
    g2 = *(const uint4*)(s2 + o2); g3 = *(const uint4*)(s3 + o3);
    g4 = *(const uint4*)(s4 + o4); g5 = *(const uint4*)(s5 + o5);

    for (int k0 = 0; k0 < 128; k0 += 32) {
        *(uint4*)d0 = g0; *(uint4*)d1 = g1; *(uint4*)d2 = g2;
        *(uint4*)d3 = g3; *(uint4*)d4 = g4; *(uint4*)d5 = g5;
        __syncthreads();

        if (k0 + 32 < 128) {
            int kn = k0 + 32;
            g0 = *(const uint4*)(s0 + o0 + kn); g1 = *(const uint4*)(s1 + o1 + kn);
            g2 = *(const uint4*)(s2 + o2 + kn); g3 = *(const uint4*)(s3 + o3 + kn);
            g4 = *(const uint4*)(s4 + o4 + kn); g5 = *(const uint4*)(s5 + o5 + kn);
        }

        bf16x8 fah = *(const bf16x8*)&sAh[quad][w * 16 + mr][0];
        bf16x8 fal = *(const bf16x8*)&sAl[quad][w * 16 + mr][0];
        #pragma unroll
        for (int j = 0; j < 8; ++j) {
            bf16x8 fbh = *(const bf16x8*)&sBh[quad][j * 16 + mr][0];
            bf16x8 fbl = *(const bf16x8*)&sBl[quad][j * 16 + mr][0];
            acc[j] = __builtin_amdgcn_mfma_f32_16x16x32_bf16(fah, fbh, acc[j], 0, 0, 0);
            acc[j] = __builtin_amdgcn_mfma_f32_16x16x32_bf16(fah, fbl, acc[j], 0, 0, 0);
            acc[j] = __builtin_amdgcn_mfma_f32_16x16x32_bf16(fal, fbh, acc[j], 0, 0, 0);
        }
        __syncthreads();
    }

    // epi[w][t-in-strip][r-local]
    #pragma unroll
    for (int j = 0; j < 8; ++j)
        #pragma unroll
        for (int r = 0; r < 4; ++r)
            epi[w][quad * 4 + r][j * 16 + mr] = acc[j][r];
    __syncthreads();

    const float* nb = nArr + (long)bh * 2048;
    #pragma unroll
    for (int i = 0; i < 16; ++i) {
        int id = i * 256 + tid;           // 64 t x 64 j
        int tl = id >> 6, j = id & 63;
        int t  = t0 + tl;
        int r  = t - j;
        int rc = r < 0 ? 0 : r;
        int rl = tl - j + 64;             // in [1,127]
        float S  = epi[tl >> 4][tl & 15][rl];
        float d2 = nb[t] + nb[rc] - 2.0f * S;
        band[((long)bh * 2048 + t) * 64 + j] = d2;
    }
}

// ---------------------------------------------------------------------------
// sig chain (QV row stride 2048, Q = cols 0..1023)
// ---------------------------------------------------------------------------
__global__ void sig_part(const float* __restrict__ QV, float* __restrict__ P)
{
    int j  = blockIdx.x * 256 + threadIdx.x;
    int tc = blockIdx.y;
    int b  = blockIdx.z;
    float s = 0.f, s8 = 0.f;
    int t0 = tc * 256;
    for (int t = t0; t < t0 + 256; ++t) {
        float v = QV[((long)(b * T_ + t)) * 2048 + j];
        s += v;
        if ((t & 7) == 0) s8 += v;
    }
    long o = ((long)b * 8 + tc) * 1024 + j;
    P[o * 2]     = s;
    P[o * 2 + 1] = s8;
}

__global__ void sig_fin(const float* __restrict__ P, float* __restrict__ sig)
{
    int j = blockIdx.x * 256 + threadIdx.x;
    int b = blockIdx.y;
    float s = 0.f, s8 = 0.f;
    for (int tc = 0; tc < 8; ++tc) {
        long o = ((long)b * 8 + tc) * 1024 + j;
        s  += P[o * 2];
        s8 += P[o * 2 + 1];
    }
    sig[b * 1024 + j] = s * (1.0f / 2048.0f) + 0.5f * s8 * (1.0f / 256.0f);
}

__global__ void mlp1(const float* __restrict__ sig, const float* __restrict__ w1,
                     const float* __restrict__ b1, float* __restrict__ H)
{
    int o = blockIdx.x * 256 + threadIdx.x;
    int b = blockIdx.y;
    float a = 0.f;
    for (int k = 0; k < 1024; ++k)
        a += sig[b * 1024 + k] * w1[(long)k * 512 + o];
    a += b1[o];
    H[b * 512 + o] = 0.5f * a * (1.0f + erff(a * 0.70710678118f));
}

__global__ void mlp2(const float* __restrict__ H, const float* __restrict__ w2,
                     const float* __restrict__ b2, const float* __restrict__ base,
                     float* __restrict__ metric)
{
    int c = blockIdx.x * 256 + threadIdx.x;
    int b = blockIdx.y;
    float a = 0.f;
    for (int k = 0; k < 512; ++k)
        a += H[b * 512 + k] * w2[(long)k * 1024 + c];
    float mv = base[c] + 0.1f * (a + b2[c]);
    metric[b * 1024 + c] = fmaxf(mv, 0.f) + log1pf(expf(-fabsf(mv)));
}

// MhT[h][e][f] = sum_r U[h][f][r] * V[h][r][e], bf16 out
__global__ void hebbmat(const float* __restrict__ U, const float* __restrict__ Vh,
                        u16* __restrict__ MhT)
{
    int gid = blockIdx.x * 256 + threadIdx.x;
    int h = gid >> 14;
    int rem = gid & 16383;
    int e = rem >> 7;
    int f = rem & 127;
    float a = 0.f;
    #pragma unroll
    for (int r = 0; r < 32; ++r)
        a += U[(h * 128 + f) * 32 + r] * Vh[(h * 32 + r) * 128 + e];
    MhT[(h * 128 + e) * 128 + f] = f2bf(a);
}

// ---------------------------------------------------------------------------
// Context kernel v3: distance phase replaced by band load (dist_gemm output).
// j=0 (r=t) special-cased to d^2=0 exactly (only cancellation-unsafe entry).
// Clamped j>t candidates read band[t][t] = d^2(t,0), ties broken by j.
// ---------------------------------------------------------------------------
__global__ __launch_bounds__(256) void context_k(
    const float* __restrict__ QV, const float* __restrict__ band,
    const u16* __restrict__ HEBbf,
    u16* __restrict__ CTh, u16* __restrict__ CTl)
{
    __shared__ float wv[4][32];
    __shared__ int   wi[4][32];

    const int w    = threadIdx.x >> 6;
    const int lane = threadIdx.x & 63;
    const int gw   = blockIdx.x * 4 + w;
    const int h    = gw & 7;
    const int bt   = gw >> 3;
    const int t    = bt & (T_ - 1);
    const int b    = bt >> 11;
    const int bh   = b * 8 + h;

    const long qrow  = (long)bt * 2048 + h * 128;
    const long ctrow = (long)bt * 1024 + h * 128;

    float q0 = QV[qrow + lane], q1 = QV[qrow + 64 + lane];
    float ss = q0 * q0 + q1 * q1;
    #pragma unroll
    for (int s = 32; s; s >>= 1) ss += __shfl_xor(ss, s, 64);
    const float qn  = sqrtf(ss);
    const float inv = 1.0f / fmaxf(qn, 1e-12f);

    int je = lane < t ? lane : t;
    float d2v = (je == 0) ? 0.f
              : band[((long)bh * 2048 + t) * 64 + je];
    float d = sqrtf(fmaxf(d2v, 0.f) + 1e-8f);
    int jj = lane;

    for (int k = 2; k <= 64; k <<= 1) {
        for (int s = k >> 1; s >= 1; s >>= 1) {
            float od = __shfl_xor(d, s, 64);
            int   oj = __shfl_xor(jj, s, 64);
            bool up    = ((lane & k) == 0);
            bool lower = ((lane & s) == 0);
            bool osm   = (od < d) || (od == d && oj < jj);
            if ((lower == up) ? osm : !osm) { d = od; jj = oj; }
        }
    }

    float wexp = (lane < 32) ? expf(-d) : 0.f;
    float tot = wexp;
    #pragma unroll
    for (int s = 32; s; s >>= 1) tot += __shfl_xor(tot, s, 64);
    float wn = wexp / (tot + 1e-8f);
    if (lane < 32) {
        wv[w][lane] = wn;
        int ii = t - jj; if (ii < 0) ii = 0;
        wi[w][lane] = ii;
    }

    float c0 = 0.f, c1 = 0.f;
    #pragma unroll 4
    for (int k = 0; k < 32; ++k) {
        float wk = wv[w][k];
        long vb = ((long)(b * T_ + wi[w][k])) * 2048 + 1024 + h * 128;
        c0 += wk * QV[vb + lane];
        c1 += wk * QV[vb + 64 + lane];
    }

    if (qn > 0.2f) {
        float s = 0.1f * inv;
        c0 += s * bf2f(HEBbf[ctrow + lane]);
        c1 += s * bf2f(HEBbf[ctrow + 64 + lane]);
    }

    u16 hh, ll;
    split1(q0 * c0, hh, ll);
    CTh[ctrow + lane] = hh; CTl[ctrow + lane] = ll;
    split1(q1 * c1, hh, ll);
    CTh[ctrow + 64 + lane] = hh; CTl[ctrow + 64 + lane] = ll;
}

// ---------------------------------------------------------------------------
extern "C" void kernel_launch(void* const* d_in, const int* in_sizes, int n_in,
                              void* d_out, int out_size, void* d_ws, size_t ws_size,
                              hipStream_t stream)
{
    const float* x     = (const float*)d_in[0];
    const float* enc_q = (const float*)d_in[1];
    const float* enc_v = (const float*)d_in[2];
    const float* w1    = (const float*)d_in[3];
    const float* b1    = (const float*)d_in[4];
    const float* w2    = (const float*)d_in[5];
    const float* b2    = (const float*)d_in[6];
    const float* base  = (const float*)d_in[7];
    const float* hU    = (const float*)d_in[8];
    const float* hV    = (const float*)d_in[9];
    const float* dec   = (const float*)d_in[10];
    float* out = (float*)d_out;
    float* ws  = (float*)d_ws;

    // ws (floats), peak 12.75M = 51 MB:
    float* QV  = ws;                        // [0, 8388608) fp32 [4096][2048]
    u16* wTh   = (u16*)(ws + 8388608);      // dead after QV gemm
    u16* wTl   = (u16*)(ws + 9437184);
    u16* Uhp   = (u16*)(ws + 8388608);      // U hi  [8388608,10485760) after wT dead
    u16* Ulp   = (u16*)(ws + 10485760);     // U lo  [10485760,12582912)
    u16* CTh   = (u16*)(ws + 8388608);      // after U dead (context output)
    u16* CTl   = (u16*)(ws + 10485760);
    u16* MhT   = (u16*)(ws + 12582912);     // dead after heb_gemm
    float* nA  = ws + 12582912;             // 32768 fp32 norms, after MhT dead
    float* P   = ws + 12713984;
    float* sg  = ws + 12746752;
    float* Hh  = ws + 12748800;
    float* Me  = ws + 12749824;
    u16* wdTh  = (u16*)ws;                  // QV region, dead after context_k
    u16* wdTl  = (u16*)(ws + 524288);
    u16* xh    = (u16*)d_out;               // staging in d_out
    u16* xl    = xh + 4194304;
    u16* Qbf   = (u16*)d_out;               // after xh dead; dead after heb_gemm
    u16* HEBbf = (u16*)d_out + 4194304;     // after xl dead
    float* band = (float*)d_out;            // 2*8*2048*64 fp32 = 8MB, after Qbf dead

    cvt_split<<<4096, 256, 0, stream>>>(x, xh, xl, 4194304);

    cvt_wT<<<dim3(32, 32), 256, 0, stream>>>(enc_q, wTh, wTl, 1024, 7, 127, 131072L, 128);
    cvt_wT<<<dim3(32, 32), 256, 0, stream>>>(enc_v, wTh + 1048576, wTl + 1048576,
                                             1024, 7, 127, 131072L, 128);
    gemm_mfma<<<512, 256, 0, stream>>>(xh, xl, wTh, wTl, QV, 4096, 2048, 1024, 1);

    qcvt<<<4096, 256, 0, stream>>>(QV, Qbf);

    sig_part<<<dim3(4, 8, 2), 256, 0, stream>>>(QV, P);
    sig_fin <<<dim3(4, 2),    256, 0, stream>>>(P, sg);
    mlp1    <<<dim3(2, 2),    256, 0, stream>>>(sg, w1, b1, Hh);
    mlp2    <<<dim3(4, 2),    256, 0, stream>>>(Hh, w2, b2, base, Me);
    hebbmat <<<512,           256, 0, stream>>>(hU, hV, MhT);
    heb_gemm<<<dim3(32, 8),   256, 0, stream>>>(Qbf, MhT, HEBbf);

    // distance pipeline: stage U (+norms), banded MFMA distances
    ustage   <<<4096, 256, 0, stream>>>(QV, Me, Uhp, Ulp, nA);
    dist_gemm<<<512,  256, 0, stream>>>(Uhp, Ulp, nA, band);

    context_k<<<8192, 256, 0, stream>>>(QV, band, HEBbf, CTh, CTl);

    cvt_wT<<<dim3(32, 32), 256, 0, stream>>>(dec, wdTh, wdTl, 1024, 30, 0x3fffffff, 0L, 1024);
    gemm_mfma<<<256, 256, 0, stream>>>(CTh, CTl, wdTh, wdTl, out, 4096, 1024, 1024, 0);
}

// Round 9
// 382.846 us; speedup vs baseline: 1.6606x; 1.0088x over previous
//
#include <hip/hip_runtime.h>
#include <math.h>

#define T_ 2048
#define NH_ 8
#define HD_ 128

typedef unsigned short u16;
typedef short bf16x8 __attribute__((ext_vector_type(8)));
typedef float f32x4 __attribute__((ext_vector_type(4)));

__device__ __forceinline__ u16 f2bf(float f)
{
    unsigned u = __float_as_uint(f);
    return (u16)((u + 0x7FFFu + ((u >> 16) & 1u)) >> 16);
}
__device__ __forceinline__ float bf2f(u16 h)
{
    return __uint_as_float(((unsigned)h) << 16);
}
// fp32 -> (hi, lo) bf16 split; a ~= hi + lo, rel err ~2^-17
__device__ __forceinline__ void split1(float f, u16& h, u16& l)
{
    h = f2bf(f);
    l = f2bf(f - bf2f(h));
}

// ---------------------------------------------------------------------------
// cvt_split_pk: x [4096][1024] fp32 -> hi/lo bf16 in K-major packed layout
// [k/32][4096][32] (a K-step's 64-row tile is contiguous -> coalesced staging).
// ---------------------------------------------------------------------------
__global__ __launch_bounds__(256) void cvt_split_pk(const float* __restrict__ in,
                                                    u16* __restrict__ hi,
                                                    u16* __restrict__ lo)
{
    int i = (blockIdx.x * 256 + threadIdx.x) * 4;
    int m = i >> 10, k = i & 1023;
    float4 v = *(const float4*)&in[i];
    u16 h0, l0, h1, l1, h2, l2, h3, l3;
    split1(v.x, h0, l0); split1(v.y, h1, l1);
    split1(v.z, h2, l2); split1(v.w, h3, l3);
    ushort4 hv = {h0, h1, h2, h3}, lv = {l0, l1, l2, l3};
    long o = (long)(k >> 5) * 131072 + m * 32 + (k & 31);
    *(ushort4*)&hi[o] = hv;
    *(ushort4*)&lo[o] = lv;
}

// ---------------------------------------------------------------------------
// Weight convert -> K-major packed [k/32][Ntot][32] bf16 hi/lo.
// Bw element (k,c) at (c>>cs)*sn + k*sk + (c&cm).  grid (Kd/32, Ncols/32).
// ---------------------------------------------------------------------------
__global__ __launch_bounds__(256) void cvt_wT_pk(const float* __restrict__ Bw,
                                                 u16* __restrict__ WTh,
                                                 u16* __restrict__ WTl,
                                                 int Kd, int cs, int cm, long sn, int sk,
                                                 int Ntot, int nofs)
{
    __shared__ u16 tH[32][33], tL[32][33];
    const int tid = threadIdx.x;
    const int tx = tid & 31, ty = tid >> 5;
    const int k0 = blockIdx.x * 32, c0 = blockIdx.y * 32;
    #pragma unroll
    for (int r = 0; r < 4; ++r) {
        int k = k0 + ty * 4 + r;
        int c = c0 + tx;
        float v = Bw[(long)(c >> cs) * sn + (long)k * sk + (c & cm)];
        u16 h, l; split1(v, h, l);
        tH[ty * 4 + r][tx] = h;
        tL[ty * 4 + r][tx] = l;
    }
    __syncthreads();
    #pragma unroll
    for (int r = 0; r < 4; ++r) {
        int n = c0 + ty * 4 + r;
        long o = (long)blockIdx.x * Ntot * 32 + (long)(nofs + n) * 32 + tx;
        WTh[o] = tH[tx][ty * 4 + r];
        WTl[o] = tL[tx][ty * 4 + r];
    }
}

// ---------------------------------------------------------------------------
// Split-bf16 MFMA GEMM v6: BARRIER-FREE wave-private pipeline.
// Each wave owns a 64x64 quadrant and stages its own A/B hi/lo tiles into
// 16 KB wave-private LDS -> no __syncthreads in the K-loop -> no vmcnt(0)
// drain (the structural stall of rounds 3-8); prefetch loads stay in flight
// across the whole MFMA phase.  Per-wave DS in-order exec guarantees
// read(k) -> write(k+1) ordering in the single-buffered LDS.
// Operands are K-major packed [k/32][rows][32] -> staging loads fully
// coalesced (4 lines/instr, not 64).
// ---------------------------------------------------------------------------
__global__ __launch_bounds__(256, 1) void gemm_mfma(
    const u16* __restrict__ Ah, const u16* __restrict__ Al,
    const u16* __restrict__ Bh, const u16* __restrict__ Bl,
    float* __restrict__ C, int M, int N, int Kd, int relu)
{
    __shared__ __align__(16) u16 S[4][8192];   // 16 KB per wave

    const int tid  = threadIdx.x;
    const int w    = tid >> 6;
    const int lane = tid & 63;

    // XCD swizzle: m-tiles = M/128 (32); xcd = id&7 owns 4 m-strips, n-major
    const int id   = blockIdx.x;
    const int m0   = (((id & 7) << 2) + ((id >> 3) & 3)) * 128;
    const int n0   = (id >> 5) * 128;

    const int mw   = (w & 1) * 64, nw = (w >> 1) * 64;
    const int mr   = lane & 15, quad = lane >> 4;

    const long Astr = (long)M * 32, Bstr = (long)N * 32;
    const u16* gAh = Ah + (long)(m0 + mw) * 32;
    const u16* gAl = Al + (long)(m0 + mw) * 32;
    const u16* gBh = Bh + (long)(n0 + nw) * 32;
    const u16* gBl = Bl + (long)(n0 + nw) * 32;

    u16* W = &S[w][0];   // [mat:4][kq:4][row:64][8] u16

    f32x4 acc[4][4] = {};
    uint4 ah0, ah1, ah2, ah3, al0, al1, al2, al3;
    uint4 bh0, bh1, bh2, bh3, bl0, bl1, bl2, bl3;

#define LOADG(KT) do { long ta = (long)(KT) * Astr, tb = (long)(KT) * Bstr;          \
    ah0 = *(const uint4*)(gAh + ta +    0 + lane * 8);                               \
    ah1 = *(const uint4*)(gAh + ta +  512 + lane * 8);                               \
    ah2 = *(const uint4*)(gAh + ta + 1024 + lane * 8);                               \
    ah3 = *(const uint4*)(gAh + ta + 1536 + lane * 8);                               \
    al0 = *(const uint4*)(gAl + ta +    0 + lane * 8);                               \
    al1 = *(const uint4*)(gAl + ta +  512 + lane * 8);                               \
    al2 = *(const uint4*)(gAl + ta + 1024 + lane * 8);                               \
    al3 = *(const uint4*)(gAl + ta + 1536 + lane * 8);                               \
    bh0 = *(const uint4*)(gBh + tb +    0 + lane * 8);                               \
    bh1 = *(const uint4*)(gBh + tb +  512 + lane * 8);                               \
    bh2 = *(const uint4*)(gBh + tb + 1024 + lane * 8);                               \
    bh3 = *(const uint4*)(gBh + tb + 1536 + lane * 8);                               \
    bl0 = *(const uint4*)(gBl + tb +    0 + lane * 8);                               \
    bl1 = *(const uint4*)(gBl + tb +  512 + lane * 8);                               \
    bl2 = *(const uint4*)(gBl + tb + 1024 + lane * 8);                               \
    bl3 = *(const uint4*)(gBl + tb + 1536 + lane * 8); } while (0)

    // chunk c holds rows c*16+(lane>>2), kq=lane&3 -> LDS [kq][row][8]
#define STOREG() do { u16* D = W + (lane & 3) * 512 + (lane >> 2) * 8;               \
    *(uint4*)(D +    0) = ah0; *(uint4*)(D +  128) = ah1;                            \
    *(uint4*)(D +  256) = ah2; *(uint4*)(D +  384) = ah3;                            \
    *(uint4*)(D + 2048) = al0; *(uint4*)(D + 2176) = al1;                            \
    *(uint4*)(D + 2304) = al2; *(uint4*)(D + 2432) = al3;                            \
    *(uint4*)(D + 4096) = bh0; *(uint4*)(D + 4224) = bh1;                            \
    *(uint4*)(D + 4352) = bh2; *(uint4*)(D + 4480) = bh3;                            \
    *(uint4*)(D + 6144) = bl0; *(uint4*)(D + 6272) = bl1;                            \
    *(uint4*)(D + 6400) = bl2; *(uint4*)(D + 6528) = bl3; } while (0)

    LOADG(0);
    STOREG();
    LOADG(1);

    const int NT = Kd >> 5;
    for (int kt = 0; kt < NT; ++kt) {
        bf16x8 fah[4], fal[4], fbh[4], fbl[4];
        #pragma unroll
        for (int i = 0; i < 4; ++i) {
            int ro = quad * 512 + (i * 16 + mr) * 8;
            fah[i] = *(const bf16x8*)(W + ro);
            fal[i] = *(const bf16x8*)(W + 2048 + ro);
            fbh[i] = *(const bf16x8*)(W + 4096 + ro);
            fbl[i] = *(const bf16x8*)(W + 6144 + ro);
        }
        if (kt + 1 < NT) STOREG();         // in-order DS: safe after the reads
        if (kt + 2 < NT) LOADG(kt + 2);    // stays in flight: no barrier drains
        #pragma unroll
        for (int i = 0; i < 4; ++i)
            #pragma unroll
            for (int j = 0; j < 4; ++j) {
                acc[i][j] = __builtin_amdgcn_mfma_f32_16x16x32_bf16(fah[i], fbh[j], acc[i][j], 0, 0, 0);
                acc[i][j] = __builtin_amdgcn_mfma_f32_16x16x32_bf16(fah[i], fbl[j], acc[i][j], 0, 0, 0);
                acc[i][j] = __builtin_amdgcn_mfma_f32_16x16x32_bf16(fal[i], fbh[j], acc[i][j], 0, 0, 0);
            }
    }
#undef LOADG
#undef STOREG

    #pragma unroll
    for (int i = 0; i < 4; ++i)
        #pragma unroll
        for (int j = 0; j < 4; ++j)
            #pragma unroll
            for (int r = 0; r < 4; ++r) {
                int row = m0 + mw + i * 16 + quad * 4 + r;
                int col = n0 + nw + j * 16 + mr;
                float v = acc[i][j][r];
                if (relu) v = fmaxf(v, 0.f);
                C[(long)row * N + col] = v;
            }
}

// ---------------------------------------------------------------------------
// HEB = bf16(Q) @ MhT[h], batched over heads (unchanged).
// ---------------------------------------------------------------------------
__global__ __launch_bounds__(256) void heb_gemm(
    const u16* __restrict__ Qbf, const u16* __restrict__ MhT,
    u16* __restrict__ HEBbf)
{
    __shared__ __align__(16) u16 sA[4][128][8], sB[4][128][8];

    const int tid  = threadIdx.x;
    const int w    = tid >> 6;
    const int lane = tid & 63;
    const int m0   = blockIdx.x * 128;
    const int h    = blockIdx.y;
    const int mw   = w * 32;
    const int mr   = lane & 15, quad = lane >> 4;
    const u16* Bm  = MhT + h * 16384;

    f32x4 acc[2][8] = {};

    for (int k0 = 0; k0 < 128; k0 += 32) {
        #pragma unroll
        for (int u = 0; u < 4; ++u) {
            int c = (w & 1) * 4 + u;
            int kq = c >> 1, half = c & 1;
            const u16* src; u16* dst; long gofs;
            if (w < 2) {
                src = Qbf;
                dst = &sA[0][0][0] + kq * 1024 + half * 512;
                gofs = (long)(m0 + half * 64 + lane) * 1024 + h * 128 + k0 + kq * 8;
            } else {
                src = Bm;
                dst = &sB[0][0][0] + kq * 1024 + half * 512;
                gofs = (long)(half * 64 + lane) * 128 + k0 + kq * 8;
            }
            __builtin_amdgcn_global_load_lds(
                (const __attribute__((address_space(1))) unsigned int*)(src + gofs),
                (__attribute__((address_space(3))) unsigned int*)dst, 16, 0, 0);
        }
        __syncthreads();

        bf16x8 fa[2], fb[8];
        #pragma unroll
        for (int i = 0; i < 2; ++i)
            fa[i] = *(const bf16x8*)&sA[quad][mw + i * 16 + mr][0];
        #pragma unroll
        for (int j = 0; j < 8; ++j)
            fb[j] = *(const bf16x8*)&sB[quad][j * 16 + mr][0];
        #pragma unroll
        for (int i = 0; i < 2; ++i)
            #pragma unroll
            for (int j = 0; j < 8; ++j)
                acc[i][j] = __builtin_amdgcn_mfma_f32_16x16x32_bf16(fa[i], fb[j], acc[i][j], 0, 0, 0);
        __syncthreads();
    }

    #pragma unroll
    for (int i = 0; i < 2; ++i)
        #pragma unroll
        for (int j = 0; j < 8; ++j)
            #pragma unroll
            for (int r = 0; r < 4; ++r) {
                int row = m0 + mw + i * 16 + quad * 4 + r;
                int col = h * 128 + j * 16 + mr;
                HEBbf[(long)row * 1024 + col] = f2bf(acc[i][j][r]);
            }
}

// ---------------------------------------------------------------------------
// qu_stage (fused qcvt + ustage): one QV read -> Qbf bf16, U hi/lo, |u|^2.
// ---------------------------------------------------------------------------
__global__ __launch_bounds__(256) void qu_stage(const float* __restrict__ QV,
                                                const float* __restrict__ Me,
                                                u16* __restrict__ Qbf,
                                                u16* __restrict__ Uh, u16* __restrict__ Ul,
                                                float* __restrict__ nArr)
{
    int gid4 = (blockIdx.x * 256 + threadIdx.x) * 4;   // over 2*8*2048*128
    int e4 = gid4 & 127;
    int t  = (gid4 >> 7) & 2047;
    int bh = gid4 >> 18;
    int b  = bh >> 3, h = bh & 7;
    float4 q = *(const float4*)&QV[((long)(b * 2048 + t)) * 2048 + h * 128 + e4];
    ushort4 qo = {f2bf(q.x), f2bf(q.y), f2bf(q.z), f2bf(q.w)};
    *(ushort4*)&Qbf[((long)(b * 2048 + t)) * 1024 + h * 128 + e4] = qo;

    float4 m = *(const float4*)&Me[bh * 128 + e4];
    float ux = sqrtf(m.x) * q.x, uy = sqrtf(m.y) * q.y;
    float uz = sqrtf(m.z) * q.z, uw = sqrtf(m.w) * q.w;
    u16 h0, l0, h1, l1, h2, l2, h3, l3;
    split1(ux, h0, l0); split1(uy, h1, l1);
    split1(uz, h2, l2); split1(uw, h3, l3);
    ushort4 hv = {h0, h1, h2, h3}, lv = {l0, l1, l2, l3};
    *(ushort4*)&Uh[gid4] = hv;
    *(ushort4*)&Ul[gid4] = lv;
    float ps = ux * ux + uy * uy + uz * uz + uw * uw;
    #pragma unroll
    for (int mm = 16; mm; mm >>= 1) ps += __shfl_xor(ps, mm, 64);
    if ((threadIdx.x & 31) == 0) nArr[gid4 >> 7] = ps;
}

// ---------------------------------------------------------------------------
// dist_gemm: banded d^2 via split-bf16 MFMA (unchanged from round 8).
// ---------------------------------------------------------------------------
__global__ __launch_bounds__(256, 1) void dist_gemm(
    const u16* __restrict__ Uh, const u16* __restrict__ Ul,
    const float* __restrict__ nArr, float* __restrict__ band)
{
    __shared__ __align__(16) u16 sAh[4][64][8],  sAl[4][64][8];
    __shared__ __align__(16) u16 sBh[4][128][8], sBl[4][128][8];
    __shared__ float epi[4][16][128];

    const int tid  = threadIdx.x;
    const int w    = tid >> 6;
    const int lane = tid & 63;
    const int mr   = lane & 15, quad = lane >> 4;
    const int bid  = blockIdx.x;
    const int tile = bid & 31, bh = bid >> 5;
    const int t0   = tile * 64;
    const long ub  = (long)bh * 2048 * 128;

    const u16 *s0, *s1, *s2, *s3, *s4, *s5;
    u16 *d0, *d1, *d2, *d3, *d4, *d5;
    long o0, o1, o2, o3, o4, o5;
    {
        auto mk = [&](int i, const u16*& src, u16*& dst, long& ofs) {
            int c = i * 256 + tid;
            if (c < 512) {
                int row = c & 63, kq = (c >> 6) & 3;
                src = (c < 256) ? Uh : Ul;
                ofs = ub + (long)(t0 + row) * 128 + kq * 8;
                dst = ((c < 256) ? &sAh[0][0][0] : &sAl[0][0][0]) + kq * 512 + row * 8;
            } else {
                int cb = c - 512;
                int row = cb & 127, kq = (cb >> 7) & 3;
                src = (cb < 512) ? Uh : Ul;
                ofs = ub + (long)(t0 - 64 + row) * 128 + kq * 8;
                dst = ((cb < 512) ? &sBh[0][0][0] : &sBl[0][0][0]) + kq * 1024 + row * 8;
            }
        };
        mk(0, s0, d0, o0); mk(1, s1, d1, o1); mk(2, s2, d2, o2);
        mk(3, s3, d3, o3); mk(4, s4, d4, o4); mk(5, s5, d5, o5);
    }

    f32x4 acc[8] = {};
    uint4 g0, g1, g2, g3, g4, g5;
    g0 = *(const uint4*)(s0 + o0); g1 = *(const uint4*)(s1 + o1);
    g2 = *(const uint4*)(s2 + o2); g3 = *(const uint4*)(s3 + o3);
    g4 = *(const uint4*)(s4 + o4); g5 = *(const uint4*)(s5 + o5);

    for (int k0 = 0; k0 < 128; k0 += 32) {
        *(uint4*)d0 = g0; *(uint4*)d1 = g1; *(uint4*)d2 = g2;
        *(uint4*)d3 = g3; *(uint4*)d4 = g4; *(uint4*)d5 = g5;
        __syncthreads();

        if (k0 + 32 < 128) {
            int kn = k0 + 32;
            g0 = *(const uint4*)(s0 + o0 + kn); g1 = *(const uint4*)(s1 + o1 + kn);
            g2 = *(const uint4*)(s2 + o2 + kn); g3 = *(const uint4*)(s3 + o3 + kn);
            g4 = *(const uint4*)(s4 + o4 + kn); g5 = *(const uint4*)(s5 + o5 + kn);
        }

        bf16x8 fah = *(const bf16x8*)&sAh[quad][w * 16 + mr][0];
        bf16x8 fal = *(const bf16x8*)&sAl[quad][w * 16 + mr][0];
        #pragma unroll
        for (int j = 0; j < 8; ++j) {
            bf16x8 fbh = *(const bf16x8*)&sBh[quad][j * 16 + mr][0];
            bf16x8 fbl = *(const bf16x8*)&sBl[quad][j * 16 + mr][0];
            acc[j] = __builtin_amdgcn_mfma_f32_16x16x32_bf16(fah, fbh, acc[j], 0, 0, 0);
            acc[j] = __builtin_amdgcn_mfma_f32_16x16x32_bf16(fah, fbl, acc[j], 0, 0, 0);
            acc[j] = __builtin_amdgcn_mfma_f32_16x16x32_bf16(fal, fbh, acc[j], 0, 0, 0);
        }
        __syncthreads();
    }

    #pragma unroll
    for (int j = 0; j < 8; ++j)
        #pragma unroll
        for (int r = 0; r < 4; ++r)
            epi[w][quad * 4 + r][j * 16 + mr] = acc[j][r];
    __syncthreads();

    const float* nb = nArr + (long)bh * 2048;
    #pragma unroll
    for (int i = 0; i < 16; ++i) {
        int id = i * 256 + tid;
        int tl = id >> 6, j = id & 63;
        int t  = t0 + tl;
        int r  = t - j;
        int rc = r < 0 ? 0 : r;
        int rl = tl - j + 64;
        float S  = epi[tl >> 4][tl & 15][rl];
        float d2 = nb[t] + nb[rc] - 2.0f * S;
        band[((long)bh * 2048 + t) * 64 + j] = d2;
    }
}

// ---------------------------------------------------------------------------
// sig chain (QV row stride 2048, Q = cols 0..1023)
// ---------------------------------------------------------------------------
__global__ void sig_part(const float* __restrict__ QV, float* __restrict__ P)
{
    int j  = blockIdx.x * 256 + threadIdx.x;
    int tc = blockIdx.y;
    int b  = blockIdx.z;
    float s = 0.f, s8 = 0.f;
    int t0 = tc * 256;
    for (int t = t0; t < t0 + 256; ++t) {
        float v = QV[((long)(b * T_ + t)) * 2048 + j];
        s += v;
        if ((t & 7) == 0) s8 += v;
    }
    long o = ((long)b * 8 + tc) * 1024 + j;
    P[o * 2]     = s;
    P[o * 2 + 1] = s8;
}

__global__ void sig_fin(const float* __restrict__ P, float* __restrict__ sig)
{
    int j = blockIdx.x * 256 + threadIdx.x;
    int b = blockIdx.y;
    float s = 0.f, s8 = 0.f;
    for (int tc = 0; tc < 8; ++tc) {
        long o = ((long)b * 8 + tc) * 1024 + j;
        s  += P[o * 2];
        s8 += P[o * 2 + 1];
    }
    sig[b * 1024 + j] = s * (1.0f / 2048.0f) + 0.5f * s8 * (1.0f / 256.0f);
}

__global__ void mlp1(const float* __restrict__ sig, const float* __restrict__ w1,
                     const float* __restrict__ b1, float* __restrict__ H)
{
    int o = blockIdx.x * 256 + threadIdx.x;
    int b = blockIdx.y;
    float a = 0.f;
    for (int k = 0; k < 1024; ++k)
        a += sig[b * 1024 + k] * w1[(long)k * 512 + o];
    a += b1[o];
    H[b * 512 + o] = 0.5f * a * (1.0f + erff(a * 0.70710678118f));
}

__global__ void mlp2(const float* __restrict__ H, const float* __restrict__ w2,
                     const float* __restrict__ b2, const float* __restrict__ base,
                     float* __restrict__ metric)
{
    int c = blockIdx.x * 256 + threadIdx.x;
    int b = blockIdx.y;
    float a = 0.f;
    for (int k = 0; k < 512; ++k)
        a += H[b * 512 + k] * w2[(long)k * 1024 + c];
    float mv = base[c] + 0.1f * (a + b2[c]);
    metric[b * 1024 + c] = fmaxf(mv, 0.f) + log1pf(expf(-fabsf(mv)));
}

// MhT[h][e][f] = sum_r U[h][f][r] * V[h][r][e], bf16 out
__global__ void hebbmat(const float* __restrict__ U, const float* __restrict__ Vh,
                        u16* __restrict__ MhT)
{
    int gid = blockIdx.x * 256 + threadIdx.x;
    int h = gid >> 14;
    int rem = gid & 16383;
    int e = rem >> 7;
    int f = rem & 127;
    float a = 0.f;
    #pragma unroll
    for (int r = 0; r < 32; ++r)
        a += U[(h * 128 + f) * 32 + r] * Vh[(h * 32 + r) * 128 + e];
    MhT[(h * 128 + e) * 128 + f] = f2bf(a);
}

// ---------------------------------------------------------------------------
// Context kernel v4: as round 8, but CT epilogue writes K-major packed layout
// [c/32][4096][32] for the barrier-free decoder GEMM.
// ---------------------------------------------------------------------------
__global__ __launch_bounds__(256) void context_k(
    const float* __restrict__ QV, const float* __restrict__ band,
    const u16* __restrict__ HEBbf,
    u16* __restrict__ CTh, u16* __restrict__ CTl)
{
    __shared__ float wv[4][32];
    __shared__ int   wi[4][32];

    const int w    = threadIdx.x >> 6;
    const int lane = threadIdx.x & 63;
    const int gw   = blockIdx.x * 4 + w;
    const int h    = gw & 7;
    const int bt   = gw >> 3;
    const int t    = bt & (T_ - 1);
    const int b    = bt >> 11;
    const int bh   = b * 8 + h;

    const long qrow  = (long)bt * 2048 + h * 128;
    const long hrow  = (long)bt * 1024 + h * 128;

    float q0 = QV[qrow + lane], q1 = QV[qrow + 64 + lane];
    float ss = q0 * q0 + q1 * q1;
    #pragma unroll
    for (int s = 32; s; s >>= 1) ss += __shfl_xor(ss, s, 64);
    const float qn  = sqrtf(ss);
    const float inv = 1.0f / fmaxf(qn, 1e-12f);

    int je = lane < t ? lane : t;
    float d2v = (je == 0) ? 0.f
              : band[((long)bh * 2048 + t) * 64 + je];
    float d = sqrtf(fmaxf(d2v, 0.f) + 1e-8f);
    int jj = lane;

    for (int k = 2; k <= 64; k <<= 1) {
        for (int s = k >> 1; s >= 1; s >>= 1) {
            float od = __shfl_xor(d, s, 64);
            int   oj = __shfl_xor(jj, s, 64);
            bool up    = ((lane & k) == 0);
            bool lower = ((lane & s) == 0);
            bool osm   = (od < d) || (od == d && oj < jj);
            if ((lower == up) ? osm : !osm) { d = od; jj = oj; }
        }
    }

    float wexp = (lane < 32) ? expf(-d) : 0.f;
    float tot = wexp;
    #pragma unroll
    for (int s = 32; s; s >>= 1) tot += __shfl_xor(tot, s, 64);
    float wn = wexp / (tot + 1e-8f);
    if (lane < 32) {
        wv[w][lane] = wn;
        int ii = t - jj; if (ii < 0) ii = 0;
        wi[w][lane] = ii;
    }

    float c0 = 0.f, c1 = 0.f;
    #pragma unroll 8
    for (int k = 0; k < 32; ++k) {
        float wk = wv[w][k];
        long vb = ((long)(b * T_ + wi[w][k])) * 2048 + 1024 + h * 128;
        c0 += wk * QV[vb + lane];
        c1 += wk * QV[vb + 64 + lane];
    }

    if (qn > 0.2f) {
        float s = 0.1f * inv;
        c0 += s * bf2f(HEBbf[hrow + lane]);
        c1 += s * bf2f(HEBbf[hrow + 64 + lane]);
    }

    // packed CT write: col c = h*128 + lane (and +64)
    long po0 = (long)(h * 4 + (lane >> 5)) * 131072 + (long)bt * 32 + (lane & 31);
    long po1 = (long)(h * 4 + 2 + (lane >> 5)) * 131072 + (long)bt * 32 + (lane & 31);
    u16 hh, ll;
    split1(q0 * c0, hh, ll);
    CTh[po0] = hh; CTl[po0] = ll;
    split1(q1 * c1, hh, ll);
    CTh[po1] = hh; CTl[po1] = ll;
}

// ---------------------------------------------------------------------------
extern "C" void kernel_launch(void* const* d_in, const int* in_sizes, int n_in,
                              void* d_out, int out_size, void* d_ws, size_t ws_size,
                              hipStream_t stream)
{
    const float* x     = (const float*)d_in[0];
    const float* enc_q = (const float*)d_in[1];
    const float* enc_v = (const float*)d_in[2];
    const float* w1    = (const float*)d_in[3];
    const float* b1    = (const float*)d_in[4];
    const float* w2    = (const float*)d_in[5];
    const float* b2    = (const float*)d_in[6];
    const float* base  = (const float*)d_in[7];
    const float* hU    = (const float*)d_in[8];
    const float* hV    = (const float*)d_in[9];
    const float* dec   = (const float*)d_in[10];
    float* out = (float*)d_out;
    float* ws  = (float*)d_ws;

    // ws (floats), peak 12.75M = 51 MB:
    float* QV  = ws;                        // [0, 8388608) fp32 [4096][2048]
    u16* wTh   = (u16*)(ws + 8388608);      // packed, dead after QV gemm
    u16* wTl   = (u16*)(ws + 9437184);
    u16* Uhp   = (u16*)(ws + 8388608);      // U hi, after wT dead
    u16* Ulp   = (u16*)(ws + 10485760);     // U lo
    u16* CTh   = (u16*)(ws + 8388608);      // packed CT, after U dead
    u16* CTl   = (u16*)(ws + 10485760);
    u16* MhT   = (u16*)(ws + 12582912);     // lives through heb_gemm
    float* P   = ws + 12713984;             // sig partials; nA after sig done
    float* nA  = ws + 12713984;
    float* sg  = ws + 12746752;
    float* Hh  = ws + 12748800;
    float* Me  = ws + 12749824;
    u16* wdTh  = (u16*)ws;                  // QV region, dead after context_k
    u16* wdTl  = (u16*)(ws + 524288);
    u16* xh    = (u16*)d_out;               // packed x staging in d_out
    u16* xl    = xh + 4194304;
    u16* Qbf   = (u16*)d_out;               // after xh dead; dead after heb_gemm
    u16* HEBbf = (u16*)d_out + 4194304;     // after xl dead
    float* band = (float*)d_out;            // 8 MB, after Qbf dead

    cvt_split_pk<<<4096, 256, 0, stream>>>(x, xh, xl);

    // merged packed weights: enc_q -> cols 0..1023, enc_v -> 1024..2047
    cvt_wT_pk<<<dim3(32, 32), 256, 0, stream>>>(enc_q, wTh, wTl, 1024, 7, 127, 131072L, 128, 2048, 0);
    cvt_wT_pk<<<dim3(32, 32), 256, 0, stream>>>(enc_v, wTh, wTl, 1024, 7, 127, 131072L, 128, 2048, 1024);
    // QV = relu(x @ [enc_q | enc_v]) — barrier-free waveGEMM, 512 blocks
    gemm_mfma<<<512, 256, 0, stream>>>(xh, xl, wTh, wTl, QV, 4096, 2048, 1024, 1);

    sig_part<<<dim3(4, 8, 2), 256, 0, stream>>>(QV, P);
    sig_fin <<<dim3(4, 2),    256, 0, stream>>>(P, sg);
    mlp1    <<<dim3(2, 2),    256, 0, stream>>>(sg, w1, b1, Hh);
    mlp2    <<<dim3(4, 2),    256, 0, stream>>>(Hh, w2, b2, base, Me);
    hebbmat <<<512,           256, 0, stream>>>(hU, hV, MhT);

    qu_stage<<<4096, 256, 0, stream>>>(QV, Me, Qbf, Uhp, Ulp, nA);
    heb_gemm<<<dim3(32, 8), 256, 0, stream>>>(Qbf, MhT, HEBbf);
    dist_gemm<<<512, 256, 0, stream>>>(Uhp, Ulp, nA, band);   // band over Qbf

    context_k<<<8192, 256, 0, stream>>>(QV, band, HEBbf, CTh, CTl);

    // out = CT @ decoder — packed, barrier-free waveGEMM
    cvt_wT_pk<<<dim3(32, 32), 256, 0, stream>>>(dec, wdTh, wdTl, 1024, 30, 0x3fffffff, 0L, 1024, 1024, 0);
    gemm_mfma<<<256, 256, 0, stream>>>(CTh, CTl, wdTh, wdTl, out, 4096, 1024, 1024, 0);
}

// Round 10
// 356.094 us; speedup vs baseline: 1.7854x; 1.0751x over previous
//
#include <hip/hip_runtime.h>
#include <math.h>

#define T_ 2048
#define NH_ 8
#define HD_ 128

typedef unsigned short u16;
typedef short bf16x8 __attribute__((ext_vector_type(8)));
typedef float f32x4 __attribute__((ext_vector_type(4)));

__device__ __forceinline__ u16 f2bf(float f)
{
    unsigned u = __float_as_uint(f);
    return (u16)((u + 0x7FFFu + ((u >> 16) & 1u)) >> 16);
}
__device__ __forceinline__ float bf2f(u16 h)
{
    return __uint_as_float(((unsigned)h) << 16);
}
// fp32 -> (hi, lo) bf16 split; a ~= hi + lo, rel err ~2^-17
__device__ __forceinline__ void split1(float f, u16& h, u16& l)
{
    h = f2bf(f);
    l = f2bf(f - bf2f(h));
}

// packed layout (mirrors the GEMM's LDS layout so staging is lane-linear on
// both sides): offset(row, k; Kd) = (row>>6)*(Kd*64) + (k>>5)*2048
//                                 + ((k>>3)&3)*512 + (row&63)*8 + (k&7)

// ---------------------------------------------------------------------------
// cvt_split_pk: x [4096][1024] fp32 -> hi/lo bf16, packed layout.
// ---------------------------------------------------------------------------
__global__ __launch_bounds__(256) void cvt_split_pk(const float* __restrict__ in,
                                                    u16* __restrict__ hi,
                                                    u16* __restrict__ lo)
{
    int i = (blockIdx.x * 256 + threadIdx.x) * 4;
    int m = i >> 10, k = i & 1023;
    float4 v = *(const float4*)&in[i];
    u16 h0, l0, h1, l1, h2, l2, h3, l3;
    split1(v.x, h0, l0); split1(v.y, h1, l1);
    split1(v.z, h2, l2); split1(v.w, h3, l3);
    ushort4 hv = {h0, h1, h2, h3}, lv = {l0, l1, l2, l3};
    long o = (long)(m >> 6) * 65536 + (k >> 5) * 2048
           + ((k >> 3) & 3) * 512 + (m & 63) * 8 + (k & 7);
    *(ushort4*)&hi[o] = hv;
    *(ushort4*)&lo[o] = lv;
}

// ---------------------------------------------------------------------------
// Weight convert -> packed layout over the N dim (rows of the packed matrix).
// Bw element (k,c) at (c>>cs)*sn + k*sk + (c&cm).  grid (Kd/32, Ncols/32).
// ---------------------------------------------------------------------------
__global__ __launch_bounds__(256) void cvt_wT_pk(const float* __restrict__ Bw,
                                                 u16* __restrict__ WTh,
                                                 u16* __restrict__ WTl,
                                                 int Kd, int cs, int cm, long sn, int sk,
                                                 int nofs)
{
    __shared__ u16 tH[32][33], tL[32][33];
    const int tid = threadIdx.x;
    const int tx = tid & 31, ty = tid >> 5;
    const int k0 = blockIdx.x * 32, c0 = blockIdx.y * 32;
    #pragma unroll
    for (int r = 0; r < 4; ++r) {
        int k = k0 + ty * 4 + r;
        int c = c0 + tx;
        float v = Bw[(long)(c >> cs) * sn + (long)k * sk + (c & cm)];
        u16 h, l; split1(v, h, l);
        tH[ty * 4 + r][tx] = h;
        tL[ty * 4 + r][tx] = l;
    }
    __syncthreads();
    const long sstr = (long)Kd * 64;
    #pragma unroll
    for (int r = 0; r < 4; ++r) {
        int n = nofs + c0 + ty * 4 + r;
        int k = k0 + tx;
        long o = (long)(n >> 6) * sstr + (k >> 5) * 2048
               + ((k >> 3) & 3) * 512 + (n & 63) * 8 + (k & 7);
        WTh[o] = tH[tx][ty * 4 + r];
        WTl[o] = tL[tx][ty * 4 + r];
    }
}

// ---------------------------------------------------------------------------
// Split-bf16 MFMA GEMM v7: barrier-free wave-private pipeline, conflict-free.
// Round-9's STOREG was not lane-linear -> 4-way LDS write conflicts (2.5e7).
// Global packed layout now mirrors LDS layout [kt][kq][row64][8]:
//   LOADG  = 16x 1KB-contiguous uint4 loads (perfect coalescing)
//   STOREG = W + lane*8 (+const): quarter-wave = 256B sweep, 0 conflicts
//   frag reads unchanged (already linear).
// No __syncthreads in K-loop -> no vmcnt(0) drain; per-wave DS in-order
// exec guarantees read(kt) -> write(kt+1) ordering.
// ---------------------------------------------------------------------------
__global__ __launch_bounds__(256, 1) void gemm_mfma(
    const u16* __restrict__ Ah, const u16* __restrict__ Al,
    const u16* __restrict__ Bh, const u16* __restrict__ Bl,
    float* __restrict__ C, int M, int N, int Kd, int relu)
{
    __shared__ __align__(16) u16 S[4][8192];   // 16 KB per wave

    const int tid  = threadIdx.x;
    const int w    = tid >> 6;
    const int lane = tid & 63;

    // XCD swizzle: m-tiles = M/128 (32); xcd = id&7 owns 4 m-strips, n-major
    const int id   = blockIdx.x;
    const int m0   = (((id & 7) << 2) + ((id >> 3) & 3)) * 128;
    const int n0   = (id >> 5) * 128;

    const int mw   = (w & 1) * 64, nw = (w >> 1) * 64;
    const int mr   = lane & 15, quad = lane >> 4;

    const long sstr = (long)Kd * 64;           // u16 per 64-row strip
    const u16* gAh = Ah + (long)((m0 + mw) >> 6) * sstr;
    const u16* gAl = Al + (long)((m0 + mw) >> 6) * sstr;
    const u16* gBh = Bh + (long)((n0 + nw) >> 6) * sstr;
    const u16* gBl = Bl + (long)((n0 + nw) >> 6) * sstr;

    u16* W = &S[w][0];   // [mat:4][kq:4][row:64][8] u16

    f32x4 acc[4][4] = {};
    uint4 ah0, ah1, ah2, ah3, al0, al1, al2, al3;
    uint4 bh0, bh1, bh2, bh3, bl0, bl1, bl2, bl3;

#define LOADG(KT) do { long t = (long)(KT) * 2048 + lane * 8;                        \
    ah0 = *(const uint4*)(gAh + t +    0); ah1 = *(const uint4*)(gAh + t +  512);    \
    ah2 = *(const uint4*)(gAh + t + 1024); ah3 = *(const uint4*)(gAh + t + 1536);    \
    al0 = *(const uint4*)(gAl + t +    0); al1 = *(const uint4*)(gAl + t +  512);    \
    al2 = *(const uint4*)(gAl + t + 1024); al3 = *(const uint4*)(gAl + t + 1536);    \
    bh0 = *(const uint4*)(gBh + t +    0); bh1 = *(const uint4*)(gBh + t +  512);    \
    bh2 = *(const uint4*)(gBh + t + 1024); bh3 = *(const uint4*)(gBh + t + 1536);    \
    bl0 = *(const uint4*)(gBl + t +    0); bl1 = *(const uint4*)(gBl + t +  512);    \
    bl2 = *(const uint4*)(gBl + t + 1024); bl3 = *(const uint4*)(gBl + t + 1536); } while (0)

#define STOREG() do { u16* D = W + lane * 8;                                         \
    *(uint4*)(D +    0) = ah0; *(uint4*)(D +  512) = ah1;                            \
    *(uint4*)(D + 1024) = ah2; *(uint4*)(D + 1536) = ah3;                            \
    *(uint4*)(D + 2048) = al0; *(uint4*)(D + 2560) = al1;                            \
    *(uint4*)(D + 3072) = al2; *(uint4*)(D + 3584) = al3;                            \
    *(uint4*)(D + 4096) = bh0; *(uint4*)(D + 4608) = bh1;                            \
    *(uint4*)(D + 5120) = bh2; *(uint4*)(D + 5632) = bh3;                            \
    *(uint4*)(D + 6144) = bl0; *(uint4*)(D + 6656) = bl1;                            \
    *(uint4*)(D + 7168) = bl2; *(uint4*)(D + 7680) = bl3; } while (0)

    LOADG(0);
    STOREG();
    LOADG(1);

    const int NT = Kd >> 5;
    for (int kt = 0; kt < NT; ++kt) {
        bf16x8 fah[4], fal[4], fbh[4], fbl[4];
        #pragma unroll
        for (int i = 0; i < 4; ++i) {
            int ro = quad * 512 + (i * 16 + mr) * 8;
            fah[i] = *(const bf16x8*)(W + ro);
            fal[i] = *(const bf16x8*)(W + 2048 + ro);
            fbh[i] = *(const bf16x8*)(W + 4096 + ro);
            fbl[i] = *(const bf16x8*)(W + 6144 + ro);
        }
        if (kt + 1 < NT) STOREG();         // in-order DS: safe after the reads
        if (kt + 2 < NT) LOADG(kt + 2);    // stays in flight: no barrier drains
        #pragma unroll
        for (int i = 0; i < 4; ++i)
            #pragma unroll
            for (int j = 0; j < 4; ++j) {
                acc[i][j] = __builtin_amdgcn_mfma_f32_16x16x32_bf16(fah[i], fbh[j], acc[i][j], 0, 0, 0);
                acc[i][j] = __builtin_amdgcn_mfma_f32_16x16x32_bf16(fah[i], fbl[j], acc[i][j], 0, 0, 0);
                acc[i][j] = __builtin_amdgcn_mfma_f32_16x16x32_bf16(fal[i], fbh[j], acc[i][j], 0, 0, 0);
            }
    }
#undef LOADG
#undef STOREG

    #pragma unroll
    for (int i = 0; i < 4; ++i)
        #pragma unroll
        for (int j = 0; j < 4; ++j)
            #pragma unroll
            for (int r = 0; r < 4; ++r) {
                int row = m0 + mw + i * 16 + quad * 4 + r;
                int col = n0 + nw + j * 16 + mr;
                float v = acc[i][j][r];
                if (relu) v = fmaxf(v, 0.f);
                C[(long)row * N + col] = v;
            }
}

// ---------------------------------------------------------------------------
// HEB = bf16(Q) @ MhT[h], batched over heads (unchanged).
// ---------------------------------------------------------------------------
__global__ __launch_bounds__(256) void heb_gemm(
    const u16* __restrict__ Qbf, const u16* __restrict__ MhT,
    u16* __restrict__ HEBbf)
{
    __shared__ __align__(16) u16 sA[4][128][8], sB[4][128][8];

    const int tid  = threadIdx.x;
    const int w    = tid >> 6;
    const int lane = tid & 63;
    const int m0   = blockIdx.x * 128;
    const int h    = blockIdx.y;
    const int mw   = w * 32;
    const int mr   = lane & 15, quad = lane >> 4;
    const u16* Bm  = MhT + h * 16384;

    f32x4 acc[2][8] = {};

    for (int k0 = 0; k0 < 128; k0 += 32) {
        #pragma unroll
        for (int u = 0; u < 4; ++u) {
            int c = (w & 1) * 4 + u;
            int kq = c >> 1, half = c & 1;
            const u16* src; u16* dst; long gofs;
            if (w < 2) {
                src = Qbf;
                dst = &sA[0][0][0] + kq * 1024 + half * 512;
                gofs = (long)(m0 + half * 64 + lane) * 1024 + h * 128 + k0 + kq * 8;
            } else {
                src = Bm;
                dst = &sB[0][0][0] + kq * 1024 + half * 512;
                gofs = (long)(half * 64 + lane) * 128 + k0 + kq * 8;
            }
            __builtin_amdgcn_global_load_lds(
                (const __attribute__((address_space(1))) unsigned int*)(src + gofs),
                (__attribute__((address_space(3))) unsigned int*)dst, 16, 0, 0);
        }
        __syncthreads();

        bf16x8 fa[2], fb[8];
        #pragma unroll
        for (int i = 0; i < 2; ++i)
            fa[i] = *(const bf16x8*)&sA[quad][mw + i * 16 + mr][0];
        #pragma unroll
        for (int j = 0; j < 8; ++j)
            fb[j] = *(const bf16x8*)&sB[quad][j * 16 + mr][0];
        #pragma unroll
        for (int i = 0; i < 2; ++i)
            #pragma unroll
            for (int j = 0; j < 8; ++j)
                acc[i][j] = __builtin_amdgcn_mfma_f32_16x16x32_bf16(fa[i], fb[j], acc[i][j], 0, 0, 0);
        __syncthreads();
    }

    #pragma unroll
    for (int i = 0; i < 2; ++i)
        #pragma unroll
        for (int j = 0; j < 8; ++j)
            #pragma unroll
            for (int r = 0; r < 4; ++r) {
                int row = m0 + mw + i * 16 + quad * 4 + r;
                int col = h * 128 + j * 16 + mr;
                HEBbf[(long)row * 1024 + col] = f2bf(acc[i][j][r]);
            }
}

// ---------------------------------------------------------------------------
// qu_stage (fused qcvt + ustage): one QV read -> Qbf bf16, U hi/lo, |u|^2.
// ---------------------------------------------------------------------------
__global__ __launch_bounds__(256) void qu_stage(const float* __restrict__ QV,
                                                const float* __restrict__ Me,
                                                u16* __restrict__ Qbf,
                                                u16* __restrict__ Uh, u16* __restrict__ Ul,
                                                float* __restrict__ nArr)
{
    int gid4 = (blockIdx.x * 256 + threadIdx.x) * 4;   // over 2*8*2048*128
    int e4 = gid4 & 127;
    int t  = (gid4 >> 7) & 2047;
    int bh = gid4 >> 18;
    int b  = bh >> 3, h = bh & 7;
    float4 q = *(const float4*)&QV[((long)(b * 2048 + t)) * 2048 + h * 128 + e4];
    ushort4 qo = {f2bf(q.x), f2bf(q.y), f2bf(q.z), f2bf(q.w)};
    *(ushort4*)&Qbf[((long)(b * 2048 + t)) * 1024 + h * 128 + e4] = qo;

    float4 m = *(const float4*)&Me[bh * 128 + e4];
    float ux = sqrtf(m.x) * q.x, uy = sqrtf(m.y) * q.y;
    float uz = sqrtf(m.z) * q.z, uw = sqrtf(m.w) * q.w;
    u16 h0, l0, h1, l1, h2, l2, h3, l3;
    split1(ux, h0, l0); split1(uy, h1, l1);
    split1(uz, h2, l2); split1(uw, h3, l3);
    ushort4 hv = {h0, h1, h2, h3}, lv = {l0, l1, l2, l3};
    *(ushort4*)&Uh[gid4] = hv;
    *(ushort4*)&Ul[gid4] = lv;
    float ps = ux * ux + uy * uy + uz * uz + uw * uw;
    #pragma unroll
    for (int mm = 16; mm; mm >>= 1) ps += __shfl_xor(ps, mm, 64);
    if ((threadIdx.x & 31) == 0) nArr[gid4 >> 7] = ps;
}

// ---------------------------------------------------------------------------
// dist_gemm: banded d^2 via split-bf16 MFMA (unchanged from round 8).
// ---------------------------------------------------------------------------
__global__ __launch_bounds__(256, 1) void dist_gemm(
    const u16* __restrict__ Uh, const u16* __restrict__ Ul,
    const float* __restrict__ nArr, float* __restrict__ band)
{
    __shared__ __align__(16) u16 sAh[4][64][8],  sAl[4][64][8];
    __shared__ __align__(16) u16 sBh[4][128][8], sBl[4][128][8];
    __shared__ float epi[4][16][128];

    const int tid  = threadIdx.x;
    const int w    = tid >> 6;
    const int lane = tid & 63;
    const int mr   = lane & 15, quad = lane >> 4;
    const int bid  = blockIdx.x;
    const int tile = bid & 31, bh = bid >> 5;
    const int t0   = tile * 64;
    const long ub  = (long)bh * 2048 * 128;

    const u16 *s0, *s1, *s2, *s3, *s4, *s5;
    u16 *d0, *d1, *d2, *d3, *d4, *d5;
    long o0, o1, o2, o3, o4, o5;
    {
        auto mk = [&](int i, const u16*& src, u16*& dst, long& ofs) {
            int c = i * 256 + tid;
            if (c < 512) {
                int row = c & 63, kq = (c >> 6) & 3;
                src = (c < 256) ? Uh : Ul;
                ofs = ub + (long)(t0 + row) * 128 + kq * 8;
                dst = ((c < 256) ? &sAh[0][0][0] : &sAl[0][0][0]) + kq * 512 + row * 8;
            } else {
                int cb = c - 512;
                int row = cb & 127, kq = (cb >> 7) & 3;
                src = (cb < 512) ? Uh : Ul;
                ofs = ub + (long)(t0 - 64 + row) * 128 + kq * 8;
                dst = ((cb < 512) ? &sBh[0][0][0] : &sBl[0][0][0]) + kq * 1024 + row * 8;
            }
        };
        mk(0, s0, d0, o0); mk(1, s1, d1, o1); mk(2, s2, d2, o2);
        mk(3, s3, d3, o3); mk(4, s4, d4, o4); mk(5, s5, d5, o5);
    }

    f32x4 acc[8] = {};
    uint4 g0, g1, g2, g3, g4, g5;
    g0 = *(const uint4*)(s0 + o0); g1 = *(const uint4*)(s1 + o1);
    g2 = *(const uint4*)(s2 + o2); g3 = *(const uint4*)(s3 + o3);
    g4 = *(const uint4*)(s4 + o4); g5 = *(const uint4*)(s5 + o5);

    for (int k0 = 0; k0 < 128; k0 += 32) {
        *(uint4*)d0 = g0; *(uint4*)d1 = g1; *(uint4*)d2 = g2;
        *(uint4*)d3 = g3; *(uint4*)d4 = g4; *(uint4*)d5 = g5;
        __syncthreads();

        if (k0 + 32 < 128) {
            int kn = k0 + 32;
            g0 = *(const uint4*)(s0 + o0 + kn); g1 = *(const uint4*)(s1 + o1 + kn);
            g2 = *(const uint4*)(s2 + o2 + kn); g3 = *(const uint4*)(s3 + o3 + kn);
            g4 = *(const uint4*)(s4 + o4 + kn); g5 = *(const uint4*)(s5 + o5 + kn);
        }

        bf16x8 fah = *(const bf16x8*)&sAh[quad][w * 16 + mr][0];
        bf16x8 fal = *(const bf16x8*)&sAl[quad][w * 16 + mr][0];
        #pragma unroll
        for (int j = 0; j < 8; ++j) {
            bf16x8 fbh = *(const bf16x8*)&sBh[quad][j * 16 + mr][0];
            bf16x8 fbl = *(const bf16x8*)&sBl[quad][j * 16 + mr][0];
            acc[j] = __builtin_amdgcn_mfma_f32_16x16x32_bf16(fah, fbh, acc[j], 0, 0, 0);
            acc[j] = __builtin_amdgcn_mfma_f32_16x16x32_bf16(fah, fbl, acc[j], 0, 0, 0);
            acc[j] = __builtin_amdgcn_mfma_f32_16x16x32_bf16(fal, fbh, acc[j], 0, 0, 0);
        }
        __syncthreads();
    }

    #pragma unroll
    for (int j = 0; j < 8; ++j)
        #pragma unroll
        for (int r = 0; r < 4; ++r)
            epi[w][quad * 4 + r][j * 16 + mr] = acc[j][r];
    __syncthreads();

    const float* nb = nArr + (long)bh * 2048;
    #pragma unroll
    for (int i = 0; i < 16; ++i) {
        int id = i * 256 + tid;
        int tl = id >> 6, j = id & 63;
        int t  = t0 + tl;
        int r  = t - j;
        int rc = r < 0 ? 0 : r;
        int rl = tl - j + 64;
        float S  = epi[tl >> 4][tl & 15][rl];
        float d2 = nb[t] + nb[rc] - 2.0f * S;
        band[((long)bh * 2048 + t) * 64 + j] = d2;
    }
}

// ---------------------------------------------------------------------------
// sig chain (QV row stride 2048, Q = cols 0..1023)
// ---------------------------------------------------------------------------
__global__ void sig_part(const float* __restrict__ QV, float* __restrict__ P)
{
    int j  = blockIdx.x * 256 + threadIdx.x;
    int tc = blockIdx.y;
    int b  = blockIdx.z;
    float s = 0.f, s8 = 0.f;
    int t0 = tc * 256;
    for (int t = t0; t < t0 + 256; ++t) {
        float v = QV[((long)(b * T_ + t)) * 2048 + j];
        s += v;
        if ((t & 7) == 0) s8 += v;
    }
    long o = ((long)b * 8 + tc) * 1024 + j;
    P[o * 2]     = s;
    P[o * 2 + 1] = s8;
}

__global__ void sig_fin(const float* __restrict__ P, float* __restrict__ sig)
{
    int j = blockIdx.x * 256 + threadIdx.x;
    int b = blockIdx.y;
    float s = 0.f, s8 = 0.f;
    for (int tc = 0; tc < 8; ++tc) {
        long o = ((long)b * 8 + tc) * 1024 + j;
        s  += P[o * 2];
        s8 += P[o * 2 + 1];
    }
    sig[b * 1024 + j] = s * (1.0f / 2048.0f) + 0.5f * s8 * (1.0f / 256.0f);
}

__global__ void mlp1(const float* __restrict__ sig, const float* __restrict__ w1,
                     const float* __restrict__ b1, float* __restrict__ H)
{
    int o = blockIdx.x * 256 + threadIdx.x;
    int b = blockIdx.y;
    float a = 0.f;
    for (int k = 0; k < 1024; ++k)
        a += sig[b * 1024 + k] * w1[(long)k * 512 + o];
    a += b1[o];
    H[b * 512 + o] = 0.5f * a * (1.0f + erff(a * 0.70710678118f));
}

__global__ void mlp2(const float* __restrict__ H, const float* __restrict__ w2,
                     const float* __restrict__ b2, const float* __restrict__ base,
                     float* __restrict__ metric)
{
    int c = blockIdx.x * 256 + threadIdx.x;
    int b = blockIdx.y;
    float a = 0.f;
    for (int k = 0; k < 512; ++k)
        a += H[b * 512 + k] * w2[(long)k * 1024 + c];
    float mv = base[c] + 0.1f * (a + b2[c]);
    metric[b * 1024 + c] = fmaxf(mv, 0.f) + log1pf(expf(-fabsf(mv)));
}

// MhT[h][e][f] = sum_r U[h][f][r] * V[h][r][e], bf16 out
__global__ void hebbmat(const float* __restrict__ U, const float* __restrict__ Vh,
                        u16* __restrict__ MhT)
{
    int gid = blockIdx.x * 256 + threadIdx.x;
    int h = gid >> 14;
    int rem = gid & 16383;
    int e = rem >> 7;
    int f = rem & 127;
    float a = 0.f;
    #pragma unroll
    for (int r = 0; r < 32; ++r)
        a += U[(h * 128 + f) * 32 + r] * Vh[(h * 32 + r) * 128 + e];
    MhT[(h * 128 + e) * 128 + f] = f2bf(a);
}

// ---------------------------------------------------------------------------
// Context kernel v5: CT epilogue writes the new packed layout.
// ---------------------------------------------------------------------------
__global__ __launch_bounds__(256) void context_k(
    const float* __restrict__ QV, const float* __restrict__ band,
    const u16* __restrict__ HEBbf,
    u16* __restrict__ CTh, u16* __restrict__ CTl)
{
    __shared__ float wv[4][32];
    __shared__ int   wi[4][32];

    const int w    = threadIdx.x >> 6;
    const int lane = threadIdx.x & 63;
    const int gw   = blockIdx.x * 4 + w;
    const int h    = gw & 7;
    const int bt   = gw >> 3;
    const int t    = bt & (T_ - 1);
    const int b    = bt >> 11;
    const int bh   = b * 8 + h;

    const long qrow  = (long)bt * 2048 + h * 128;
    const long hrow  = (long)bt * 1024 + h * 128;

    float q0 = QV[qrow + lane], q1 = QV[qrow + 64 + lane];
    float ss = q0 * q0 + q1 * q1;
    #pragma unroll
    for (int s = 32; s; s >>= 1) ss += __shfl_xor(ss, s, 64);
    const float qn  = sqrtf(ss);
    const float inv = 1.0f / fmaxf(qn, 1e-12f);

    int je = lane < t ? lane : t;
    float d2v = (je == 0) ? 0.f
              : band[((long)bh * 2048 + t) * 64 + je];
    float d = sqrtf(fmaxf(d2v, 0.f) + 1e-8f);
    int jj = lane;

    for (int k = 2; k <= 64; k <<= 1) {
        for (int s = k >> 1; s >= 1; s >>= 1) {
            float od = __shfl_xor(d, s, 64);
            int   oj = __shfl_xor(jj, s, 64);
            bool up    = ((lane & k) == 0);
            bool lower = ((lane & s) == 0);
            bool osm   = (od < d) || (od == d && oj < jj);
            if ((lower == up) ? osm : !osm) { d = od; jj = oj; }
        }
    }

    float wexp = (lane < 32) ? expf(-d) : 0.f;
    float tot = wexp;
    #pragma unroll
    for (int s = 32; s; s >>= 1) tot += __shfl_xor(tot, s, 64);
    float wn = wexp / (tot + 1e-8f);
    if (lane < 32) {
        wv[w][lane] = wn;
        int ii = t - jj; if (ii < 0) ii = 0;
        wi[w][lane] = ii;
    }

    float c0 = 0.f, c1 = 0.f;
    #pragma unroll 8
    for (int k = 0; k < 32; ++k) {
        float wk = wv[w][k];
        long vb = ((long)(b * T_ + wi[w][k])) * 2048 + 1024 + h * 128;
        c0 += wk * QV[vb + lane];
        c1 += wk * QV[vb + 64 + lane];
    }

    if (qn > 0.2f) {
        float s = 0.1f * inv;
        c0 += s * bf2f(HEBbf[hrow + lane]);
        c1 += s * bf2f(HEBbf[hrow + 64 + lane]);
    }

    // packed CT write (Kd=1024 -> strip stride 65536): col c = h*128+lane(+64)
    int c0c = h * 128 + lane, c1c = c0c + 64;
    long po0 = (long)(bt >> 6) * 65536 + (c0c >> 5) * 2048
             + ((c0c >> 3) & 3) * 512 + (bt & 63) * 8 + (c0c & 7);
    long po1 = (long)(bt >> 6) * 65536 + (c1c >> 5) * 2048
             + ((c1c >> 3) & 3) * 512 + (bt & 63) * 8 + (c1c & 7);
    u16 hh, ll;
    split1(q0 * c0, hh, ll);
    CTh[po0] = hh; CTl[po0] = ll;
    split1(q1 * c1, hh, ll);
    CTh[po1] = hh; CTl[po1] = ll;
}

// ---------------------------------------------------------------------------
extern "C" void kernel_launch(void* const* d_in, const int* in_sizes, int n_in,
                              void* d_out, int out_size, void* d_ws, size_t ws_size,
                              hipStream_t stream)
{
    const float* x     = (const float*)d_in[0];
    const float* enc_q = (const float*)d_in[1];
    const float* enc_v = (const float*)d_in[2];
    const float* w1    = (const float*)d_in[3];
    const float* b1    = (const float*)d_in[4];
    const float* w2    = (const float*)d_in[5];
    const float* b2    = (const float*)d_in[6];
    const float* base  = (const float*)d_in[7];
    const float* hU    = (const float*)d_in[8];
    const float* hV    = (const float*)d_in[9];
    const float* dec   = (const float*)d_in[10];
    float* out = (float*)d_out;
    float* ws  = (float*)d_ws;

    // ws (floats), peak 12.75M = 51 MB:
    float* QV  = ws;                        // [0, 8388608) fp32 [4096][2048]
    u16* wTh   = (u16*)(ws + 8388608);      // packed, dead after QV gemm
    u16* wTl   = (u16*)(ws + 9437184);
    u16* Uhp   = (u16*)(ws + 8388608);      // U hi, after wT dead
    u16* Ulp   = (u16*)(ws + 10485760);     // U lo
    u16* CTh   = (u16*)(ws + 8388608);      // packed CT, after U dead
    u16* CTl   = (u16*)(ws + 10485760);
    u16* MhT   = (u16*)(ws + 12582912);     // lives through heb_gemm
    float* P   = ws + 12713984;             // sig partials; nA after sig done
    float* nA  = ws + 12713984;
    float* sg  = ws + 12746752;
    float* Hh  = ws + 12748800;
    float* Me  = ws + 12749824;
    u16* wdTh  = (u16*)ws;                  // QV region, dead after context_k
    u16* wdTl  = (u16*)(ws + 524288);
    u16* xh    = (u16*)d_out;               // packed x staging in d_out
    u16* xl    = xh + 4194304;
    u16* Qbf   = (u16*)d_out;               // after xh dead; dead after heb_gemm
    u16* HEBbf = (u16*)d_out + 4194304;     // after xl dead
    float* band = (float*)d_out;            // 8 MB, after Qbf dead

    cvt_split_pk<<<4096, 256, 0, stream>>>(x, xh, xl);

    // merged packed weights: enc_q -> cols 0..1023, enc_v -> 1024..2047
    cvt_wT_pk<<<dim3(32, 32), 256, 0, stream>>>(enc_q, wTh, wTl, 1024, 7, 127, 131072L, 128, 0);
    cvt_wT_pk<<<dim3(32, 32), 256, 0, stream>>>(enc_v, wTh, wTl, 1024, 7, 127, 131072L, 128, 1024);
    // QV = relu(x @ [enc_q | enc_v]) — barrier-free waveGEMM, 512 blocks
    gemm_mfma<<<512, 256, 0, stream>>>(xh, xl, wTh, wTl, QV, 4096, 2048, 1024, 1);

    sig_part<<<dim3(4, 8, 2), 256, 0, stream>>>(QV, P);
    sig_fin <<<dim3(4, 2),    256, 0, stream>>>(P, sg);
    mlp1    <<<dim3(2, 2),    256, 0, stream>>>(sg, w1, b1, Hh);
    mlp2    <<<dim3(4, 2),    256, 0, stream>>>(Hh, w2, b2, base, Me);
    hebbmat <<<512,           256, 0, stream>>>(hU, hV, MhT);

    qu_stage<<<4096, 256, 0, stream>>>(QV, Me, Qbf, Uhp, Ulp, nA);
    heb_gemm<<<dim3(32, 8), 256, 0, stream>>>(Qbf, MhT, HEBbf);
    dist_gemm<<<512, 256, 0, stream>>>(Uhp, Ulp, nA, band);   // band over Qbf

    context_k<<<8192, 256, 0, stream>>>(QV, band, HEBbf, CTh, CTl);

    // out = CT @ decoder — packed, barrier-free waveGEMM
    cvt_wT_pk<<<dim3(32, 32), 256, 0, stream>>>(dec, wdTh, wdTl, 1024, 30, 0x3fffffff, 0L, 1024, 0);
    gemm_mfma<<<256, 256, 0, stream>>>(CTh, CTl, wdTh, wdTl, out, 4096, 1024, 1024, 0);
}

// Round 11
// 293.910 us; speedup vs baseline: 2.1631x; 1.2116x over previous
//
#include <hip/hip_runtime.h>
#include <math.h>

#define T_ 2048
#define NH_ 8
#define HD_ 128

typedef unsigned short u16;
typedef short bf16x8 __attribute__((ext_vector_type(8)));
typedef float f32x4 __attribute__((ext_vector_type(4)));

__device__ __forceinline__ u16 f2bf(float f)
{
    unsigned u = __float_as_uint(f);
    return (u16)((u + 0x7FFFu + ((u >> 16) & 1u)) >> 16);
}
__device__ __forceinline__ float bf2f(u16 h)
{
    return __uint_as_float(((unsigned)h) << 16);
}
// fp32 -> (hi, lo) bf16 split; a ~= hi + lo, rel err ~2^-17
__device__ __forceinline__ void split1(float f, u16& h, u16& l)
{
    h = f2bf(f);
    l = f2bf(f - bf2f(h));
}

// packed layout (mirrors the GEMM's LDS layout so staging is lane-linear on
// both sides): offset(row, k; Kd) = (row>>6)*(Kd*64) + (k>>5)*2048
//                                 + ((k>>3)&3)*512 + (row&63)*8 + (k&7)

// ---------------------------------------------------------------------------
// cvt_split_pk: x [4096][1024] fp32 -> hi/lo bf16, packed layout.
// ---------------------------------------------------------------------------
__global__ __launch_bounds__(256) void cvt_split_pk(const float* __restrict__ in,
                                                    u16* __restrict__ hi,
                                                    u16* __restrict__ lo)
{
    int i = (blockIdx.x * 256 + threadIdx.x) * 4;
    int m = i >> 10, k = i & 1023;
    float4 v = *(const float4*)&in[i];
    u16 h0, l0, h1, l1, h2, l2, h3, l3;
    split1(v.x, h0, l0); split1(v.y, h1, l1);
    split1(v.z, h2, l2); split1(v.w, h3, l3);
    ushort4 hv = {h0, h1, h2, h3}, lv = {l0, l1, l2, l3};
    long o = (long)(m >> 6) * 65536 + (k >> 5) * 2048
           + ((k >> 3) & 3) * 512 + (m & 63) * 8 + (k & 7);
    *(ushort4*)&hi[o] = hv;
    *(ushort4*)&lo[o] = lv;
}

// ---------------------------------------------------------------------------
// Weight convert -> packed layout over the N dim (rows of the packed matrix).
// Bw element (k,c) at (c>>cs)*sn + k*sk + (c&cm).  grid (Kd/32, Ncols/32).
// ---------------------------------------------------------------------------
__global__ __launch_bounds__(256) void cvt_wT_pk(const float* __restrict__ Bw,
                                                 u16* __restrict__ WTh,
                                                 u16* __restrict__ WTl,
                                                 int Kd, int cs, int cm, long sn, int sk,
                                                 int nofs)
{
    __shared__ u16 tH[32][33], tL[32][33];
    const int tid = threadIdx.x;
    const int tx = tid & 31, ty = tid >> 5;
    const int k0 = blockIdx.x * 32, c0 = blockIdx.y * 32;
    #pragma unroll
    for (int r = 0; r < 4; ++r) {
        int k = k0 + ty * 4 + r;
        int c = c0 + tx;
        float v = Bw[(long)(c >> cs) * sn + (long)k * sk + (c & cm)];
        u16 h, l; split1(v, h, l);
        tH[ty * 4 + r][tx] = h;
        tL[ty * 4 + r][tx] = l;
    }
    __syncthreads();
    const long sstr = (long)Kd * 64;
    #pragma unroll
    for (int r = 0; r < 4; ++r) {
        int n = nofs + c0 + ty * 4 + r;
        int k = k0 + tx;
        long o = (long)(n >> 6) * sstr + (k >> 5) * 2048
               + ((k >> 3) & 3) * 512 + (n & 63) * 8 + (k & 7);
        WTh[o] = tH[tx][ty * 4 + r];
        WTl[o] = tL[tx][ty * 4 + r];
    }
}

// ---------------------------------------------------------------------------
// Split-bf16 MFMA GEMM v7: barrier-free wave-private pipeline, conflict-free
// (round 10, proven: 0 bank conflicts, MfmaUtil 38%).
// ---------------------------------------------------------------------------
__global__ __launch_bounds__(256, 1) void gemm_mfma(
    const u16* __restrict__ Ah, const u16* __restrict__ Al,
    const u16* __restrict__ Bh, const u16* __restrict__ Bl,
    float* __restrict__ C, int M, int N, int Kd, int relu)
{
    __shared__ __align__(16) u16 S[4][8192];   // 16 KB per wave

    const int tid  = threadIdx.x;
    const int w    = tid >> 6;
    const int lane = tid & 63;

    const int id   = blockIdx.x;
    const int m0   = (((id & 7) << 2) + ((id >> 3) & 3)) * 128;
    const int n0   = (id >> 5) * 128;

    const int mw   = (w & 1) * 64, nw = (w >> 1) * 64;
    const int mr   = lane & 15, quad = lane >> 4;

    const long sstr = (long)Kd * 64;           // u16 per 64-row strip
    const u16* gAh = Ah + (long)((m0 + mw) >> 6) * sstr;
    const u16* gAl = Al + (long)((m0 + mw) >> 6) * sstr;
    const u16* gBh = Bh + (long)((n0 + nw) >> 6) * sstr;
    const u16* gBl = Bl + (long)((n0 + nw) >> 6) * sstr;

    u16* W = &S[w][0];   // [mat:4][kq:4][row:64][8] u16

    f32x4 acc[4][4] = {};
    uint4 ah0, ah1, ah2, ah3, al0, al1, al2, al3;
    uint4 bh0, bh1, bh2, bh3, bl0, bl1, bl2, bl3;

#define LOADG(KT) do { long t = (long)(KT) * 2048 + lane * 8;                        \
    ah0 = *(const uint4*)(gAh + t +    0); ah1 = *(const uint4*)(gAh + t +  512);    \
    ah2 = *(const uint4*)(gAh + t + 1024); ah3 = *(const uint4*)(gAh + t + 1536);    \
    al0 = *(const uint4*)(gAl + t +    0); al1 = *(const uint4*)(gAl + t +  512);    \
    al2 = *(const uint4*)(gAl + t + 1024); al3 = *(const uint4*)(gAl + t + 1536);    \
    bh0 = *(const uint4*)(gBh + t +    0); bh1 = *(const uint4*)(gBh + t +  512);    \
    bh2 = *(const uint4*)(gBh + t + 1024); bh3 = *(const uint4*)(gBh + t + 1536);    \
    bl0 = *(const uint4*)(gBl + t +    0); bl1 = *(const uint4*)(gBl + t +  512);    \
    bl2 = *(const uint4*)(gBl + t + 1024); bl3 = *(const uint4*)(gBl + t + 1536); } while (0)

#define STOREG() do { u16* D = W + lane * 8;                                         \
    *(uint4*)(D +    0) = ah0; *(uint4*)(D +  512) = ah1;                            \
    *(uint4*)(D + 1024) = ah2; *(uint4*)(D + 1536) = ah3;                            \
    *(uint4*)(D + 2048) = al0; *(uint4*)(D + 2560) = al1;                            \
    *(uint4*)(D + 3072) = al2; *(uint4*)(D + 3584) = al3;                            \
    *(uint4*)(D + 4096) = bh0; *(uint4*)(D + 4608) = bh1;                            \
    *(uint4*)(D + 5120) = bh2; *(uint4*)(D + 5632) = bh3;                            \
    *(uint4*)(D + 6144) = bl0; *(uint4*)(D + 6656) = bl1;                            \
    *(uint4*)(D + 7168) = bl2; *(uint4*)(D + 7680) = bl3; } while (0)

    LOADG(0);
    STOREG();
    LOADG(1);

    const int NT = Kd >> 5;
    for (int kt = 0; kt < NT; ++kt) {
        bf16x8 fah[4], fal[4], fbh[4], fbl[4];
        #pragma unroll
        for (int i = 0; i < 4; ++i) {
            int ro = quad * 512 + (i * 16 + mr) * 8;
            fah[i] = *(const bf16x8*)(W + ro);
            fal[i] = *(const bf16x8*)(W + 2048 + ro);
            fbh[i] = *(const bf16x8*)(W + 4096 + ro);
            fbl[i] = *(const bf16x8*)(W + 6144 + ro);
        }
        if (kt + 1 < NT) STOREG();         // in-order DS: safe after the reads
        if (kt + 2 < NT) LOADG(kt + 2);    // stays in flight: no barrier drains
        #pragma unroll
        for (int i = 0; i < 4; ++i)
            #pragma unroll
            for (int j = 0; j < 4; ++j) {
                acc[i][j] = __builtin_amdgcn_mfma_f32_16x16x32_bf16(fah[i], fbh[j], acc[i][j], 0, 0, 0);
                acc[i][j] = __builtin_amdgcn_mfma_f32_16x16x32_bf16(fah[i], fbl[j], acc[i][j], 0, 0, 0);
                acc[i][j] = __builtin_amdgcn_mfma_f32_16x16x32_bf16(fal[i], fbh[j], acc[i][j], 0, 0, 0);
            }
    }
#undef LOADG
#undef STOREG

    #pragma unroll
    for (int i = 0; i < 4; ++i)
        #pragma unroll
        for (int j = 0; j < 4; ++j)
            #pragma unroll
            for (int r = 0; r < 4; ++r) {
                int row = m0 + mw + i * 16 + quad * 4 + r;
                int col = n0 + nw + j * 16 + mr;
                float v = acc[i][j][r];
                if (relu) v = fmaxf(v, 0.f);
                C[(long)row * N + col] = v;
            }
}

// ---------------------------------------------------------------------------
// HEB = bf16(Q) @ MhT[h], batched over heads (unchanged).
// ---------------------------------------------------------------------------
__global__ __launch_bounds__(256) void heb_gemm(
    const u16* __restrict__ Qbf, const u16* __restrict__ MhT,
    u16* __restrict__ HEBbf)
{
    __shared__ __align__(16) u16 sA[4][128][8], sB[4][128][8];

    const int tid  = threadIdx.x;
    const int w    = tid >> 6;
    const int lane = tid & 63;
    const int m0   = blockIdx.x * 128;
    const int h    = blockIdx.y;
    const int mw   = w * 32;
    const int mr   = lane & 15, quad = lane >> 4;
    const u16* Bm  = MhT + h * 16384;

    f32x4 acc[2][8] = {};

    for (int k0 = 0; k0 < 128; k0 += 32) {
        #pragma unroll
        for (int u = 0; u < 4; ++u) {
            int c = (w & 1) * 4 + u;
            int kq = c >> 1, half = c & 1;
            const u16* src; u16* dst; long gofs;
            if (w < 2) {
                src = Qbf;
                dst = &sA[0][0][0] + kq * 1024 + half * 512;
                gofs = (long)(m0 + half * 64 + lane) * 1024 + h * 128 + k0 + kq * 8;
            } else {
                src = Bm;
                dst = &sB[0][0][0] + kq * 1024 + half * 512;
                gofs = (long)(half * 64 + lane) * 128 + k0 + kq * 8;
            }
            __builtin_amdgcn_global_load_lds(
                (const __attribute__((address_space(1))) unsigned int*)(src + gofs),
                (__attribute__((address_space(3))) unsigned int*)dst, 16, 0, 0);
        }
        __syncthreads();

        bf16x8 fa[2], fb[8];
        #pragma unroll
        for (int i = 0; i < 2; ++i)
            fa[i] = *(const bf16x8*)&sA[quad][mw + i * 16 + mr][0];
        #pragma unroll
        for (int j = 0; j < 8; ++j)
            fb[j] = *(const bf16x8*)&sB[quad][j * 16 + mr][0];
        #pragma unroll
        for (int i = 0; i < 2; ++i)
            #pragma unroll
            for (int j = 0; j < 8; ++j)
                acc[i][j] = __builtin_amdgcn_mfma_f32_16x16x32_bf16(fa[i], fb[j], acc[i][j], 0, 0, 0);
        __syncthreads();
    }

    #pragma unroll
    for (int i = 0; i < 2; ++i)
        #pragma unroll
        for (int j = 0; j < 8; ++j)
            #pragma unroll
            for (int r = 0; r < 4; ++r) {
                int row = m0 + mw + i * 16 + quad * 4 + r;
                int col = h * 128 + j * 16 + mr;
                HEBbf[(long)row * 1024 + col] = f2bf(acc[i][j][r]);
            }
}

// ---------------------------------------------------------------------------
// qu_stage (fused qcvt + ustage): one QV read -> Qbf bf16, U hi/lo, |u|^2.
// ---------------------------------------------------------------------------
__global__ __launch_bounds__(256) void qu_stage(const float* __restrict__ QV,
                                                const float* __restrict__ Me,
                                                u16* __restrict__ Qbf,
                                                u16* __restrict__ Uh, u16* __restrict__ Ul,
                                                float* __restrict__ nArr)
{
    int gid4 = (blockIdx.x * 256 + threadIdx.x) * 4;   // over 2*8*2048*128
    int e4 = gid4 & 127;
    int t  = (gid4 >> 7) & 2047;
    int bh = gid4 >> 18;
    int b  = bh >> 3, h = bh & 7;
    float4 q = *(const float4*)&QV[((long)(b * 2048 + t)) * 2048 + h * 128 + e4];
    ushort4 qo = {f2bf(q.x), f2bf(q.y), f2bf(q.z), f2bf(q.w)};
    *(ushort4*)&Qbf[((long)(b * 2048 + t)) * 1024 + h * 128 + e4] = qo;

    float4 m = *(const float4*)&Me[bh * 128 + e4];
    float ux = sqrtf(m.x) * q.x, uy = sqrtf(m.y) * q.y;
    float uz = sqrtf(m.z) * q.z, uw = sqrtf(m.w) * q.w;
    u16 h0, l0, h1, l1, h2, l2, h3, l3;
    split1(ux, h0, l0); split1(uy, h1, l1);
    split1(uz, h2, l2); split1(uw, h3, l3);
    ushort4 hv = {h0, h1, h2, h3}, lv = {l0, l1, l2, l3};
    *(ushort4*)&Uh[gid4] = hv;
    *(ushort4*)&Ul[gid4] = lv;
    float ps = ux * ux + uy * uy + uz * uz + uw * uw;
    #pragma unroll
    for (int mm = 16; mm; mm >>= 1) ps += __shfl_xor(ps, mm, 64);
    if ((threadIdx.x & 31) == 0) nArr[gid4 >> 7] = ps;
}

// ---------------------------------------------------------------------------
// dist_gemm: banded d^2 via split-bf16 MFMA (unchanged).
// ---------------------------------------------------------------------------
__global__ __launch_bounds__(256, 1) void dist_gemm(
    const u16* __restrict__ Uh, const u16* __restrict__ Ul,
    const float* __restrict__ nArr, float* __restrict__ band)
{
    __shared__ __align__(16) u16 sAh[4][64][8],  sAl[4][64][8];
    __shared__ __align__(16) u16 sBh[4][128][8], sBl[4][128][8];
    __shared__ float epi[4][16][128];

    const int tid  = threadIdx.x;
    const int w    = tid >> 6;
    const int lane = tid & 63;
    const int mr   = lane & 15, quad = lane >> 4;
    const int bid  = blockIdx.x;
    const int tile = bid & 31, bh = bid >> 5;
    const int t0   = tile * 64;
    const long ub  = (long)bh * 2048 * 128;

    const u16 *s0, *s1, *s2, *s3, *s4, *s5;
    u16 *d0, *d1, *d2, *d3, *d4, *d5;
    long o0, o1, o2, o3, o4, o5;
    {
        auto mk = [&](int i, const u16*& src, u16*& dst, long& ofs) {
            int c = i * 256 + tid;
            if (c < 512) {
                int row = c & 63, kq = (c >> 6) & 3;
                src = (c < 256) ? Uh : Ul;
                ofs = ub + (long)(t0 + row) * 128 + kq * 8;
                dst = ((c < 256) ? &sAh[0][0][0] : &sAl[0][0][0]) + kq * 512 + row * 8;
            } else {
                int cb = c - 512;
                int row = cb & 127, kq = (cb >> 7) & 3;
                src = (cb < 512) ? Uh : Ul;
                ofs = ub + (long)(t0 - 64 + row) * 128 + kq * 8;
                dst = ((cb < 512) ? &sBh[0][0][0] : &sBl[0][0][0]) + kq * 1024 + row * 8;
            }
        };
        mk(0, s0, d0, o0); mk(1, s1, d1, o1); mk(2, s2, d2, o2);
        mk(3, s3, d3, o3); mk(4, s4, d4, o4); mk(5, s5, d5, o5);
    }

    f32x4 acc[8] = {};
    uint4 g0, g1, g2, g3, g4, g5;
    g0 = *(const uint4*)(s0 + o0); g1 = *(const uint4*)(s1 + o1);
    g2 = *(const uint4*)(s2 + o2); g3 = *(const uint4*)(s3 + o3);
    g4 = *(const uint4*)(s4 + o4); g5 = *(const uint4*)(s5 + o5);

    for (int k0 = 0; k0 < 128; k0 += 32) {
        *(uint4*)d0 = g0; *(uint4*)d1 = g1; *(uint4*)d2 = g2;
        *(uint4*)d3 = g3; *(uint4*)d4 = g4; *(uint4*)d5 = g5;
        __syncthreads();

        if (k0 + 32 < 128) {
            int kn = k0 + 32;
            g0 = *(const uint4*)(s0 + o0 + kn); g1 = *(const uint4*)(s1 + o1 + kn);
            g2 = *(const uint4*)(s2 + o2 + kn); g3 = *(const uint4*)(s3 + o3 + kn);
            g4 = *(const uint4*)(s4 + o4 + kn); g5 = *(const uint4*)(s5 + o5 + kn);
        }

        bf16x8 fah = *(const bf16x8*)&sAh[quad][w * 16 + mr][0];
        bf16x8 fal = *(const bf16x8*)&sAl[quad][w * 16 + mr][0];
        #pragma unroll
        for (int j = 0; j < 8; ++j) {
            bf16x8 fbh = *(const bf16x8*)&sBh[quad][j * 16 + mr][0];
            bf16x8 fbl = *(const bf16x8*)&sBl[quad][j * 16 + mr][0];
            acc[j] = __builtin_amdgcn_mfma_f32_16x16x32_bf16(fah, fbh, acc[j], 0, 0, 0);
            acc[j] = __builtin_amdgcn_mfma_f32_16x16x32_bf16(fah, fbl, acc[j], 0, 0, 0);
            acc[j] = __builtin_amdgcn_mfma_f32_16x16x32_bf16(fal, fbh, acc[j], 0, 0, 0);
        }
        __syncthreads();
    }

    #pragma unroll
    for (int j = 0; j < 8; ++j)
        #pragma unroll
        for (int r = 0; r < 4; ++r)
            epi[w][quad * 4 + r][j * 16 + mr] = acc[j][r];
    __syncthreads();

    const float* nb = nArr + (long)bh * 2048;
    #pragma unroll
    for (int i = 0; i < 16; ++i) {
        int id = i * 256 + tid;
        int tl = id >> 6, j = id & 63;
        int t  = t0 + tl;
        int r  = t - j;
        int rc = r < 0 ? 0 : r;
        int rl = tl - j + 64;
        float S  = epi[tl >> 4][tl & 15][rl];
        float d2 = nb[t] + nb[rc] - 2.0f * S;
        band[((long)bh * 2048 + t) * 64 + j] = d2;
    }
}

// ---------------------------------------------------------------------------
// sig chain (QV row stride 2048, Q = cols 0..1023)
// ---------------------------------------------------------------------------
__global__ void sig_part(const float* __restrict__ QV, float* __restrict__ P)
{
    int j  = blockIdx.x * 256 + threadIdx.x;
    int tc = blockIdx.y;
    int b  = blockIdx.z;
    float s = 0.f, s8 = 0.f;
    int t0 = tc * 256;
    for (int t = t0; t < t0 + 256; ++t) {
        float v = QV[((long)(b * T_ + t)) * 2048 + j];
        s += v;
        if ((t & 7) == 0) s8 += v;
    }
    long o = ((long)b * 8 + tc) * 1024 + j;
    P[o * 2]     = s;
    P[o * 2 + 1] = s8;
}

__global__ void sig_fin(const float* __restrict__ P, float* __restrict__ sig)
{
    int j = blockIdx.x * 256 + threadIdx.x;
    int b = blockIdx.y;
    float s = 0.f, s8 = 0.f;
    for (int tc = 0; tc < 8; ++tc) {
        long o = ((long)b * 8 + tc) * 1024 + j;
        s  += P[o * 2];
        s8 += P[o * 2 + 1];
    }
    sig[b * 1024 + j] = s * (1.0f / 2048.0f) + 0.5f * s8 * (1.0f / 256.0f);
}

// ---------------------------------------------------------------------------
// mlp1 split-K: grid (2, B, 32) = 128 blocks (was 4 -> 67 us latency-bound).
// Each block accumulates a 32-row k-chunk; w1 reads coalesced across o.
// ---------------------------------------------------------------------------
__global__ __launch_bounds__(256) void mlp1_part(const float* __restrict__ sig,
                                                 const float* __restrict__ w1,
                                                 float* __restrict__ Pm)
{
    int o  = blockIdx.x * 256 + threadIdx.x;   // 0..511
    int b  = blockIdx.y;
    int kc = blockIdx.z;                       // 0..31
    float a = 0.f;
    int k0 = kc * 32;
    #pragma unroll 8
    for (int k = k0; k < k0 + 32; ++k)
        a += sig[b * 1024 + k] * w1[(long)k * 512 + o];
    Pm[((b * 32) + kc) * 512 + o] = a;
}

__global__ __launch_bounds__(256) void mlp1_fin(const float* __restrict__ Pm,
                                                const float* __restrict__ b1,
                                                float* __restrict__ H)
{
    int o = blockIdx.x * 256 + threadIdx.x;
    int b = blockIdx.y;
    float a = b1[o];
    #pragma unroll
    for (int kc = 0; kc < 32; ++kc)
        a += Pm[(b * 32 + kc) * 512 + o];
    H[b * 512 + o] = 0.5f * a * (1.0f + erff(a * 0.70710678118f));
}

// ---------------------------------------------------------------------------
// mlp2 split-K: grid (4, B, 16) = 128 blocks.
// ---------------------------------------------------------------------------
__global__ __launch_bounds__(256) void mlp2_part(const float* __restrict__ H,
                                                 const float* __restrict__ w2,
                                                 float* __restrict__ Pm)
{
    int c  = blockIdx.x * 256 + threadIdx.x;   // 0..1023
    int b  = blockIdx.y;
    int kc = blockIdx.z;                       // 0..15
    float a = 0.f;
    int k0 = kc * 32;
    #pragma unroll 8
    for (int k = k0; k < k0 + 32; ++k)
        a += H[b * 512 + k] * w2[(long)k * 1024 + c];
    Pm[((b * 16) + kc) * 1024 + c] = a;
}

__global__ __launch_bounds__(256) void mlp2_fin(const float* __restrict__ Pm,
                                                const float* __restrict__ b2,
                                                const float* __restrict__ base,
                                                float* __restrict__ metric)
{
    int c = blockIdx.x * 256 + threadIdx.x;
    int b = blockIdx.y;
    float a = b2[c];
    #pragma unroll
    for (int kc = 0; kc < 16; ++kc)
        a += Pm[(b * 16 + kc) * 1024 + c];
    float mv = base[c] + 0.1f * a;
    metric[b * 1024 + c] = fmaxf(mv, 0.f) + log1pf(expf(-fabsf(mv)));
}

// MhT[h][e][f] = sum_r U[h][f][r] * V[h][r][e], bf16 out
__global__ void hebbmat(const float* __restrict__ U, const float* __restrict__ Vh,
                        u16* __restrict__ MhT)
{
    int gid = blockIdx.x * 256 + threadIdx.x;
    int h = gid >> 14;
    int rem = gid & 16383;
    int e = rem >> 7;
    int f = rem & 127;
    float a = 0.f;
    #pragma unroll
    for (int r = 0; r < 32; ++r)
        a += U[(h * 128 + f) * 32 + r] * Vh[(h * 32 + r) * 128 + e];
    MhT[(h * 128 + e) * 128 + f] = f2bf(a);
}

// ---------------------------------------------------------------------------
// Context kernel v5 (unchanged from round 10).
// ---------------------------------------------------------------------------
__global__ __launch_bounds__(256) void context_k(
    const float* __restrict__ QV, const float* __restrict__ band,
    const u16* __restrict__ HEBbf,
    u16* __restrict__ CTh, u16* __restrict__ CTl)
{
    __shared__ float wv[4][32];
    __shared__ int   wi[4][32];

    const int w    = threadIdx.x >> 6;
    const int lane = threadIdx.x & 63;
    const int gw   = blockIdx.x * 4 + w;
    const int h    = gw & 7;
    const int bt   = gw >> 3;
    const int t    = bt & (T_ - 1);
    const int b    = bt >> 11;
    const int bh   = b * 8 + h;

    const long qrow  = (long)bt * 2048 + h * 128;
    const long hrow  = (long)bt * 1024 + h * 128;

    float q0 = QV[qrow + lane], q1 = QV[qrow + 64 + lane];
    float ss = q0 * q0 + q1 * q1;
    #pragma unroll
    for (int s = 32; s; s >>= 1) ss += __shfl_xor(ss, s, 64);
    const float qn  = sqrtf(ss);
    const float inv = 1.0f / fmaxf(qn, 1e-12f);

    int je = lane < t ? lane : t;
    float d2v = (je == 0) ? 0.f
              : band[((long)bh * 2048 + t) * 64 + je];
    float d = sqrtf(fmaxf(d2v, 0.f) + 1e-8f);
    int jj = lane;

    for (int k = 2; k <= 64; k <<= 1) {
        for (int s = k >> 1; s >= 1; s >>= 1) {
            float od = __shfl_xor(d, s, 64);
            int   oj = __shfl_xor(jj, s, 64);
            bool up    = ((lane & k) == 0);
            bool lower = ((lane & s) == 0);
            bool osm   = (od < d) || (od == d && oj < jj);
            if ((lower == up) ? osm : !osm) { d = od; jj = oj; }
        }
    }

    float wexp = (lane < 32) ? expf(-d) : 0.f;
    float tot = wexp;
    #pragma unroll
    for (int s = 32; s; s >>= 1) tot += __shfl_xor(tot, s, 64);
    float wn = wexp / (tot + 1e-8f);
    if (lane < 32) {
        wv[w][lane] = wn;
        int ii = t - jj; if (ii < 0) ii = 0;
        wi[w][lane] = ii;
    }

    float c0 = 0.f, c1 = 0.f;
    #pragma unroll 8
    for (int k = 0; k < 32; ++k) {
        float wk = wv[w][k];
        long vb = ((long)(b * T_ + wi[w][k])) * 2048 + 1024 + h * 128;
        c0 += wk * QV[vb + lane];
        c1 += wk * QV[vb + 64 + lane];
    }

    if (qn > 0.2f) {
        float s = 0.1f * inv;
        c0 += s * bf2f(HEBbf[hrow + lane]);
        c1 += s * bf2f(HEBbf[hrow + 64 + lane]);
    }

    // packed CT write (Kd=1024 -> strip stride 65536): col c = h*128+lane(+64)
    int c0c = h * 128 + lane, c1c = c0c + 64;
    long po0 = (long)(bt >> 6) * 65536 + (c0c >> 5) * 2048
             + ((c0c >> 3) & 3) * 512 + (bt & 63) * 8 + (c0c & 7);
    long po1 = (long)(bt >> 6) * 65536 + (c1c >> 5) * 2048
             + ((c1c >> 3) & 3) * 512 + (bt & 63) * 8 + (c1c & 7);
    u16 hh, ll;
    split1(q0 * c0, hh, ll);
    CTh[po0] = hh; CTl[po0] = ll;
    split1(q1 * c1, hh, ll);
    CTh[po1] = hh; CTl[po1] = ll;
}

// ---------------------------------------------------------------------------
extern "C" void kernel_launch(void* const* d_in, const int* in_sizes, int n_in,
                              void* d_out, int out_size, void* d_ws, size_t ws_size,
                              hipStream_t stream)
{
    const float* x     = (const float*)d_in[0];
    const float* enc_q = (const float*)d_in[1];
    const float* enc_v = (const float*)d_in[2];
    const float* w1    = (const float*)d_in[3];
    const float* b1    = (const float*)d_in[4];
    const float* w2    = (const float*)d_in[5];
    const float* b2    = (const float*)d_in[6];
    const float* base  = (const float*)d_in[7];
    const float* hU    = (const float*)d_in[8];
    const float* hV    = (const float*)d_in[9];
    const float* dec   = (const float*)d_in[10];
    float* out = (float*)d_out;
    float* ws  = (float*)d_ws;

    // ws (floats), peak 12.75M = 51 MB:
    float* QV  = ws;                        // [0, 8388608) fp32 [4096][2048]
    u16* wTh   = (u16*)(ws + 8388608);      // packed, dead after QV gemm
    u16* wTl   = (u16*)(ws + 9437184);
    u16* Uhp   = (u16*)(ws + 8388608);      // U hi, after wT dead
    u16* Ulp   = (u16*)(ws + 10485760);     // U lo
    u16* CTh   = (u16*)(ws + 8388608);      // packed CT, after U dead
    u16* CTl   = (u16*)(ws + 10485760);
    u16* MhT   = (u16*)(ws + 12582912);     // lives through heb_gemm
    float* P   = ws + 12713984;             // sig partials; nA after sig done
    float* nA  = ws + 12713984;
    float* sg  = ws + 12746752;
    float* Hh  = ws + 12748800;
    float* Me  = ws + 12749824;
    u16* wdTh  = (u16*)ws;                  // QV region, dead after context_k
    u16* wdTl  = (u16*)(ws + 524288);
    u16* xh    = (u16*)d_out;               // packed x staging in d_out
    u16* xl    = xh + 4194304;
    u16* Qbf   = (u16*)d_out;               // after xh dead; dead after heb_gemm
    u16* HEBbf = (u16*)d_out + 4194304;     // after xl dead
    float* band = (float*)d_out;            // 8 MB, after Qbf dead
    // mlp split-K partials: d_out region is dead between QV gemm and qu_stage
    float* Pm1 = (float*)d_out;             // 2*32*512  = 32768 fp32
    float* Pm2 = (float*)d_out + 32768;     // 2*16*1024 = 32768 fp32

    cvt_split_pk<<<4096, 256, 0, stream>>>(x, xh, xl);

    // merged packed weights: enc_q -> cols 0..1023, enc_v -> 1024..2047
    cvt_wT_pk<<<dim3(32, 32), 256, 0, stream>>>(enc_q, wTh, wTl, 1024, 7, 127, 131072L, 128, 0);
    cvt_wT_pk<<<dim3(32, 32), 256, 0, stream>>>(enc_v, wTh, wTl, 1024, 7, 127, 131072L, 128, 1024);
    // QV = relu(x @ [enc_q | enc_v]) — barrier-free waveGEMM, 512 blocks
    gemm_mfma<<<512, 256, 0, stream>>>(xh, xl, wTh, wTl, QV, 4096, 2048, 1024, 1);

    sig_part <<<dim3(4, 8, 2),  256, 0, stream>>>(QV, P);
    sig_fin  <<<dim3(4, 2),     256, 0, stream>>>(P, sg);
    mlp1_part<<<dim3(2, 2, 32), 256, 0, stream>>>(sg, w1, Pm1);
    mlp1_fin <<<dim3(2, 2),     256, 0, stream>>>(Pm1, b1, Hh);
    mlp2_part<<<dim3(4, 2, 16), 256, 0, stream>>>(Hh, w2, Pm2);
    mlp2_fin <<<dim3(4, 2),     256, 0, stream>>>(Pm2, b2, base, Me);
    hebbmat  <<<512,            256, 0, stream>>>(hU, hV, MhT);

    qu_stage<<<4096, 256, 0, stream>>>(QV, Me, Qbf, Uhp, Ulp, nA);
    heb_gemm<<<dim3(32, 8), 256, 0, stream>>>(Qbf, MhT, HEBbf);
    dist_gemm<<<512, 256, 0, stream>>>(Uhp, Ulp, nA, band);   // band over Qbf

    context_k<<<8192, 256, 0, stream>>>(QV, band, HEBbf, CTh, CTl);

    // out = CT @ decoder — packed, barrier-free waveGEMM
    cvt_wT_pk<<<dim3(32, 32), 256, 0, stream>>>(dec, wdTh, wdTl, 1024, 30, 0x3fffffff, 0L, 1024, 0);
    gemm_mfma<<<256, 256, 0, stream>>>(CTh, CTl, wdTh, wdTl, out, 4096, 1024, 1024, 0);
}